// Round 13
// baseline (1327.271 us; speedup 1.0000x reference)
//
#include <hip/hip_runtime.h>
#include <stdint.h>

#define N_TOK   16384
#define DMODEL  1024
#define NEXP    8
#define DFF     4096
#define CAP     8192
#define MAXB2   264          // 32768/128 + 8 (per-expert 128-row padding)
#define W_LOAD_C 0.01f

typedef __attribute__((ext_vector_type(8))) short short8;
typedef __attribute__((ext_vector_type(4))) float f32x4;

__device__ __forceinline__ uint16_t f2bf(float f) {
    uint32_t u = __float_as_uint(f);
    uint32_t r = u + 0x7fffu + ((u >> 16) & 1u);
    return (uint16_t)(r >> 16);
}
__device__ __forceinline__ float bf2f(uint16_t u) {
    return __uint_as_float((uint32_t)u << 16);
}

__device__ __forceinline__ float gelu_tanh(float v) {
    float u = 0.7978845608028654f * (v + 0.044715f * v * v * v);
    float ex = __expf(2.0f * u);
    float th = 1.0f - 2.0f / (ex + 1.0f);
    return 0.5f * v * (1.0f + th);
}

__device__ __forceinline__ void glds16(const uint16_t* g, uint16_t* l) {
    __builtin_amdgcn_global_load_lds(
        (const __attribute__((address_space(1))) void*)g,
        (__attribute__((address_space(3))) void*)l, 16, 0, 0);
}

// ---------------- gating + routing + load-loss + fused x->bf16 ----------------
// Dot-product code kept bitwise-identical to the passing rounds.
__global__ __launch_bounds__(512) void gating_kernel(
    const float* __restrict__ x, const float* __restrict__ noise,
    const float* __restrict__ gate_w, const float* __restrict__ noise_w,
    int* __restrict__ cnt, float* __restrict__ loadAcc,
    int* __restrict__ rowlist, float* __restrict__ slotw,
    int* __restrict__ tpos0, int* __restrict__ tpos1,
    float* __restrict__ tw0, float* __restrict__ tw1,
    uint16_t* __restrict__ xb)
{
    __shared__ float lp[8][8];
    __shared__ int   se1[8], se2[8];
    __shared__ float sw1[8], sw2[8];

    const int lane = threadIdx.x & 63;
    const int wid  = threadIdx.x >> 6;
    const int t = blockIdx.x * 8 + wid;

    const float* xr = x + (size_t)t * DMODEL;
    uint16_t* xbr = xb + (size_t)t * DMODEL;
    float ag[8] = {0,0,0,0,0,0,0,0};
    float an[8] = {0,0,0,0,0,0,0,0};
    for (int j = 0; j < 16; ++j) {
        int idx = j * 64 + lane;
        float xv = xr[idx];
        xbr[idx] = f2bf(xv);
        const float4* gp  = (const float4*)(gate_w  + idx * 8);
        const float4* np_ = (const float4*)(noise_w + idx * 8);
        float4 g0 = gp[0], g1 = gp[1];
        float4 n0 = np_[0], n1 = np_[1];
        ag[0] += xv * g0.x; ag[1] += xv * g0.y; ag[2] += xv * g0.z; ag[3] += xv * g0.w;
        ag[4] += xv * g1.x; ag[5] += xv * g1.y; ag[6] += xv * g1.z; ag[7] += xv * g1.w;
        an[0] += xv * n0.x; an[1] += xv * n0.y; an[2] += xv * n0.z; an[3] += xv * n0.w;
        an[4] += xv * n1.x; an[5] += xv * n1.y; an[6] += xv * n1.z; an[7] += xv * n1.w;
    }
    #pragma unroll
    for (int m = 32; m >= 1; m >>= 1) {
        #pragma unroll
        for (int e = 0; e < 8; ++e) {
            ag[e] += __shfl_xor(ag[e], m, 64);
            an[e] += __shfl_xor(an[e], m, 64);
        }
    }
    float logit[8], sdv[8];
    #pragma unroll
    for (int e = 0; e < 8; ++e) {
        float a = an[e];
        float sp = (a > 20.0f) ? a : log1pf(expf(a));
        sdv[e] = sp;
        logit[e] = ag[e] + noise[(size_t)t * 8 + e] * sp;
    }
    float v1 = -1e30f, v2 = -1e30f, v3 = -1e30f; int i1 = 0, i2 = 0;
    #pragma unroll
    for (int e = 0; e < 8; ++e) {
        float v = logit[e];
        if (v > v1)      { v3 = v2; v2 = v1; i2 = i1; v1 = v; i1 = e; }
        else if (v > v2) { v3 = v2; v2 = v; i2 = e; }
        else if (v > v3) { v3 = v; }
    }
    if (lane < 8) {
        float kth = (lane == i1 || lane == i2) ? v3 : v2;
        float z = (logit[lane] - kth) / sdv[lane];
        lp[wid][lane] = 0.5f * erfcf(-z * 0.70710678118654752440f);
    }
    if (lane == 0) {
        float e2 = expf(v2 - v1);
        float inv = 1.0f / (1.0f + e2);
        se1[wid] = i1; se2[wid] = i2;
        sw1[wid] = inv; sw2[wid] = e2 * inv;
        tw0[t] = inv; tw1[t] = e2 * inv;
    }
    __syncthreads();
    if (threadIdx.x < 8) {
        int e = threadIdx.x;
        float s = 0.f;
        #pragma unroll
        for (int w = 0; w < 8; ++w) s += lp[w][e];
        atomicAdd(&loadAcc[e], s);
        int m = 0;
        #pragma unroll
        for (int w = 0; w < 8; ++w) m += (se1[w] == e) + (se2[w] == e);
        if (m > 0) {
            int b = atomicAdd(&cnt[e], m);
            #pragma unroll
            for (int w = 0; w < 8; ++w) {
                int tok = blockIdx.x * 8 + w;
                if (se1[w] == e) {
                    if (b < CAP) { rowlist[e * CAP + b] = tok; slotw[e * CAP + b] = sw1[w]; }
                    tpos0[tok] = e * 32768 + b;
                    b++;
                }
                if (se2[w] == e) {
                    if (b < CAP) { rowlist[e * CAP + b] = tok; slotw[e * CAP + b] = sw2[w]; }
                    tpos1[tok] = e * 32768 + b;
                    b++;
                }
            }
        }
    }
}

// ---------------- block map scan: expert/row per 128-row packed block ----------------
__global__ void scan_kernel(const int* __restrict__ cnt,
                            int* __restrict__ be, int* __restrict__ brow,
                            int* __restrict__ ebase)
{
    if (threadIdx.x == 0 && blockIdx.x == 0) {
        int idx = 0;
        for (int e = 0; e < NEXP; ++e) {
            int ce = cnt[e]; if (ce > CAP) ce = CAP;
            int nb = (ce + 127) >> 7;
            ebase[e] = idx * 128;   // packed base row of expert e
            for (int k = 0; k < nb; ++k) { be[idx] = e; brow[idx] = k * 128; idx++; }
        }
        for (; idx < MAXB2; ++idx) { be[idx] = -1; brow[idx] = 0; }
    }
}

// ---------------- per-expert transpose f32 [R][C] -> bf16 [C][R] ----------------
__global__ __launch_bounds__(256) void transpose_w_kernel(
    const float* __restrict__ src, uint16_t* __restrict__ dst, int R, int Cc)
{
    __shared__ float tile[32][33];
    const float* s = src + (size_t)blockIdx.z * R * Cc;
    uint16_t*    d = dst + (size_t)blockIdx.z * R * Cc;
    int c0 = blockIdx.x * 32, r0 = blockIdx.y * 32;
    int tx = threadIdx.x & 31, ty = threadIdx.x >> 5;
    #pragma unroll
    for (int rr = ty; rr < 32; rr += 8)
        tile[rr][tx] = s[(size_t)(r0 + rr) * Cc + c0 + tx];
    __syncthreads();
    #pragma unroll
    for (int rr = ty; rr < 32; rr += 8)
        d[(size_t)(c0 + rr) * R + r0 + tx] = f2bf(tile[tx][rr]);
}

// ---------------- GEMM: 128x128 tile, BK=32, 4 waves, 3 blocks/CU ----------------
// r13 on the r11 structure (3-slot ring, 12 waves/CU): two counter-driven fixes.
// (a) K-loop unrolled by 3 -> ring-slot offsets are COMPILE-TIME: ds_read slot
//     folds into the 16-bit imm (0/16384/32768 + off <= 65535), glds stage
//     offset is pointer+imm (128/192/256 B), pointers advance once per triple.
//     Kills the per-iter mod-3 magic-mul + 12 address adds (VALUBusy 38.7% was
//     ABOVE MfmaUtil 27.3% -- address math stealing SIMD issue slots).
// (b) NTST: h stored with __builtin_nontemporal_store (no L3 allocation). The
//     276 MB h write stream was flushing L3 (FETCH 1.06 GB vs ~130 MB
//     compulsory); h exceeds L3 anyway so GEMM2 reads it from HBM regardless.
//     (r4's failure was NT *reads* of h in GEMM2 -- 8x A re-fetch; not this.)
template<int KTOT, int GATHER, int GELU, int ATOMIC, int NTST>
__global__ __launch_bounds__(256, 3) void gemm_kernel(
    const uint16_t* __restrict__ Abase,
    const uint16_t* __restrict__ Bfull,
    const int*      __restrict__ rowlist,
    const float*    __restrict__ slotw,
    const int*      __restrict__ cnt,
    const int*      __restrict__ be,
    const int*      __restrict__ brow,
    const float*    __restrict__ biasFull,
    uint16_t*       __restrict__ OutBf,
    float*          __restrict__ OutF,
    int ncols, int bo)
{
    // 48 KiB: 3 ring slots x (A 8KB: subtiles 0..7 | B 8KB @ +8192).
    // Subtile = 16 rows x 32 K bf16 = 1024 B. Epilogue reuses ring as
    // 128x136 u16 arena. lsm FIRST so LDS base = 0 (imm folding).
    __shared__ uint16_t lsm[24576];
    __shared__ int   lT[128];
    __shared__ float lW[128];

    // bijective XCD swizzle (m204)
    const int nwg  = gridDim.x * gridDim.y;
    const int flat = blockIdx.y * gridDim.x + blockIdx.x;
    const int xcd = flat & 7, sid = flat >> 3;
    const int q = nwg >> 3, r8_ = nwg & 7;
    const int f2 = (xcd < r8_ ? xcd * (q + 1) : r8_ * (q + 1) + (xcd - r8_) * q) + sid;
    const int nx  = f2 % gridDim.x;
    const int rbi = f2 / gridDim.x;

    const int rb = rbi + bo;
    if (rb >= MAXB2) return;
    const int e = be[rb];
    if (e < 0) return;
    const int row0 = brow[rb];
    int ce = cnt[e]; if (ce > CAP) ce = CAP;
    const int n0 = nx * 128;

    const int t    = threadIdx.x;
    const int lane = t & 63, wid = t >> 6;          // 4 waves
    const int fr = lane & 15, ks = lane >> 4;
    const int wr = wid >> 1, wc = wid & 1;          // 2(M) x 2(N) wave grid

    if (ATOMIC) {
        if (t < 128) {
            int rr = row0 + t;
            int rc = (rr < ce) ? rr : (ce - 1);
            lT[t] = rowlist[e * CAP + rc];
            lW[t] = (rr < ce) ? slotw[e * CAP + rr] : 0.0f;
        }
        __syncthreads();
    }

    // ---- staging: instr j (0,1) fills subtile wid+4j; lane l covers bytes
    // [l*16, l*16+16). st_16x32 inverse swizzle on the SOURCE granule.
    const uint16_t* Bp = Bfull + (size_t)e * ncols * KTOT;
    const int rsub = lane >> 2;
    const int kof  = ((lane & 3) ^ (((lane >> 5) & 1) << 1)) * 8;
    const int rowT0 = wid * 16 + rsub;          // subtiles 0..3
    const int rowT1 = 64 + wid * 16 + rsub;     // subtiles 4..7
    size_t gr0, gr1;
    if (GATHER) {
        int r0c = row0 + rowT0; r0c = (r0c < ce) ? r0c : (ce - 1);
        int r1c = row0 + rowT1; r1c = (r1c < ce) ? r1c : (ce - 1);
        gr0 = (size_t)rowlist[e * CAP + r0c];
        gr1 = (size_t)rowlist[e * CAP + r1c];
    } else {
        gr0 = (size_t)rbi * 128 + rowT0;
        gr1 = (size_t)rbi * 128 + rowT1;
    }
    const uint16_t* pA0 = Abase + gr0 * KTOT + kof;
    const uint16_t* pA1 = Abase + gr1 * KTOT + kof;
    const uint16_t* pB0 = Bp + (size_t)(n0 + rowT0) * KTOT + kof;
    const uint16_t* pB1 = Bp + (size_t)(n0 + rowT1) * KTOT + kof;
    const int dA0 = wid * 1024 + lane * 16;     // LDS byte offsets (linear dest)
    const int dA1 = (4 + wid) * 1024 + lane * 16;
    const int dB0 = 8192 + dA0;
    const int dB1 = 8192 + dA1;

    // ---- ds_read byte offsets within slot 0 (swizzled; conflicts = 0) ----
    const int sw = (ks * 16) ^ ((fr >> 3) << 5);
    int aOff[4], bOff[4];
    #pragma unroll
    for (int m = 0; m < 4; ++m) aOff[m] = (wr * 4 + m) * 1024 + fr * 64 + sw;
    #pragma unroll
    for (int n = 0; n < 4; ++n) bOff[n] = 8192 + (wc * 4 + n) * 1024 + fr * 64 + sw;

    f32x4 acc[4][4];
    #pragma unroll
    for (int a = 0; a < 4; ++a)
        #pragma unroll
        for (int b = 0; b < 4; ++b) acc[a][b] = (f32x4){0.f, 0.f, 0.f, 0.f};

    constexpr int NKT = KTOT / 32;
    char* lsb = (char*)lsm;

    // prologue: stage K-tiles 0,1 into slots 0,1; wait tile 0 (4 in flight)
    #pragma unroll
    for (int p = 0; p < 2; ++p) {
        char* db = lsb + p * 16384;
        glds16(pA0 + p * 32, (uint16_t*)(db + dA0));
        glds16(pA1 + p * 32, (uint16_t*)(db + dA1));
        glds16(pB0 + p * 32, (uint16_t*)(db + dB0));
        glds16(pB1 + p * 32, (uint16_t*)(db + dB1));
    }
    asm volatile("s_waitcnt vmcnt(4)" ::: "memory");
    __builtin_amdgcn_s_barrier();
    asm volatile("" ::: "memory");

    // K-loop unrolled by 3: RS_ = read slot (compile-time), SS_ = stage slot,
    // SOFF_ = stage element offset from the triple-base pointers.
#define K_STEP(KT_, RS_, SS_, SOFF_)                                         \
  {                                                                          \
    if ((KT_) + 2 < NKT) {                                                   \
      glds16(pA0 + (SOFF_), (uint16_t*)(lsb + (SS_) * 16384 + dA0));         \
      glds16(pA1 + (SOFF_), (uint16_t*)(lsb + (SS_) * 16384 + dA1));         \
      glds16(pB0 + (SOFF_), (uint16_t*)(lsb + (SS_) * 16384 + dB0));         \
      glds16(pB1 + (SOFF_), (uint16_t*)(lsb + (SS_) * 16384 + dB1));         \
    }                                                                        \
    short8 af[4], bf[4];                                                     \
    _Pragma("unroll")                                                        \
    for (int m = 0; m < 4; ++m)                                              \
      af[m] = *(const short8*)(lsb + (RS_) * 16384 + aOff[m]);               \
    _Pragma("unroll")                                                        \
    for (int n = 0; n < 4; ++n)                                              \
      bf[n] = *(const short8*)(lsb + (RS_) * 16384 + bOff[n]);               \
    __builtin_amdgcn_s_setprio(1);                                           \
    _Pragma("unroll")                                                        \
    for (int m = 0; m < 4; ++m)                                              \
      _Pragma("unroll")                                                      \
      for (int n = 0; n < 4; ++n)                                            \
        acc[m][n] = __builtin_amdgcn_mfma_f32_16x16x32_bf16(                 \
            af[m], bf[n], acc[m][n], 0, 0, 0);                               \
    __builtin_amdgcn_s_setprio(0);                                           \
    {                                                                        \
      const int rem_ = NKT - 1 - (KT_);                                      \
      if (rem_ >= 2)      asm volatile("s_waitcnt vmcnt(4)" ::: "memory");   \
      else if (rem_ == 1) asm volatile("s_waitcnt vmcnt(0)" ::: "memory");   \
    }                                                                        \
    asm volatile("" ::: "memory");                                           \
    __builtin_amdgcn_s_barrier();                                            \
    asm volatile("" ::: "memory");                                           \
  }

    for (int ktb = 0; ktb < NKT; ktb += 3) {
        K_STEP(ktb,     0, 2, 64);
        if (ktb + 1 < NKT) K_STEP(ktb + 1, 1, 0, 96);
        if (ktb + 2 < NKT) K_STEP(ktb + 2, 2, 1, 128);
        pA0 += 96; pA1 += 96; pB0 += 96; pB1 += 96;
    }
#undef K_STEP

    // ---- epilogue: D mapping col = lane&15, row = (lane>>4)*4 + j [m89/m91] ----
    const float* bias = biasFull + (size_t)e * ncols;
    if (ATOMIC) {
        #pragma unroll
        for (int mi = 0; mi < 4; ++mi) {
            const int rbase = wr * 64 + mi * 16 + ks * 4;
            #pragma unroll
            for (int ni = 0; ni < 4; ++ni) {
                const int c = n0 + wc * 64 + ni * 16 + fr;
                const float bv = bias[c];
                #pragma unroll
                for (int j = 0; j < 4; ++j) {
                    const int rl = rbase + j;
                    if (row0 + rl < ce) {
                        float v = acc[mi][ni][j] + bv;
                        atomicAdd(&OutF[(size_t)lT[rl] * DMODEL + c], lW[rl] * v);
                    }
                }
            }
        }
    } else {
        // staged, coalesced stores via the LDS arena (128 x 128 u16, stride 136)
        __syncthreads();
        #pragma unroll
        for (int mi = 0; mi < 4; ++mi) {
            #pragma unroll
            for (int ni = 0; ni < 4; ++ni) {
                const int cl = wc * 64 + ni * 16 + fr;
                const float bv = bias[n0 + cl];
                #pragma unroll
                for (int j = 0; j < 4; ++j) {
                    float v = acc[mi][ni][j] + bv;
                    if (GELU) v = gelu_tanh(v);
                    const int rl = wr * 64 + mi * 16 + ks * 4 + j;
                    lsm[rl * 136 + cl] = f2bf(v);
                }
            }
        }
        __syncthreads();
        const int r2 = t >> 1, hcol = (t & 1) * 64;
        uint16_t* gp = OutBf + ((size_t)rbi * 128 + r2) * ncols + n0 + hcol;
        #pragma unroll
        for (int j2 = 0; j2 < 8; ++j2) {
            short8 v = *(const short8*)&lsm[r2 * 136 + hcol + j2 * 8];
            if (NTST) __builtin_nontemporal_store(v, (short8*)(gp + j2 * 8));
            else      *(short8*)(gp + j2 * 8) = v;
        }
    }
}

// ---------------- combine: out[t] = w0*y2[p0] + w1*y2[p1] (gather, no atomics) ----
__global__ __launch_bounds__(256) void combine_kernel(
    const uint16_t* __restrict__ y2,
    const int* __restrict__ tpos0, const int* __restrict__ tpos1,
    const float* __restrict__ tw0, const float* __restrict__ tw1,
    const int* __restrict__ ebase, float* __restrict__ out)
{
    const int wid = threadIdx.x >> 6, lane = threadIdx.x & 63;
    const int t = blockIdx.x * 4 + wid;
    const int p0 = tpos0[t], p1 = tpos1[t];
    const int e0 = p0 >> 15, s0 = p0 & 32767;
    const int e1 = p1 >> 15, s1 = p1 & 32767;
    const bool v0 = s0 < CAP, v1 = s1 < CAP;
    const float w0 = v0 ? tw0[t] : 0.0f;
    const float w1 = v1 ? tw1[t] : 0.0f;
    const uint16_t* r0p = y2 + ((size_t)ebase[e0] + (v0 ? s0 : 0)) * DMODEL;
    const uint16_t* r1p = y2 + ((size_t)ebase[e1] + (v1 ? s1 : 0)) * DMODEL;
    float* op = out + (size_t)t * DMODEL;
    #pragma unroll
    for (int half = 0; half < 2; ++half) {
        const int off = half * 512 + lane * 8;
        short8 a = *(const short8*)(r0p + off);
        short8 b = *(const short8*)(r1p + off);
        float4 o0, o1;
        o0.x = w0 * bf2f((uint16_t)a[0]) + w1 * bf2f((uint16_t)b[0]);
        o0.y = w0 * bf2f((uint16_t)a[1]) + w1 * bf2f((uint16_t)b[1]);
        o0.z = w0 * bf2f((uint16_t)a[2]) + w1 * bf2f((uint16_t)b[2]);
        o0.w = w0 * bf2f((uint16_t)a[3]) + w1 * bf2f((uint16_t)b[3]);
        o1.x = w0 * bf2f((uint16_t)a[4]) + w1 * bf2f((uint16_t)b[4]);
        o1.y = w0 * bf2f((uint16_t)a[5]) + w1 * bf2f((uint16_t)b[5]);
        o1.z = w0 * bf2f((uint16_t)a[6]) + w1 * bf2f((uint16_t)b[6]);
        o1.w = w0 * bf2f((uint16_t)a[7]) + w1 * bf2f((uint16_t)b[7]);
        *(float4*)(op + off)     = o0;
        *(float4*)(op + off + 4) = o1;
    }
}

// ---------------- load-loss finalize ----------------
__global__ void finalize_kernel(const float* __restrict__ loadAcc, float* __restrict__ out) {
    if (threadIdx.x == 0) {
        float m = 0.f;
        #pragma unroll
        for (int e = 0; e < 8; ++e) m += loadAcc[e];
        m *= 0.125f;
        float v = 0.f;
        #pragma unroll
        for (int e = 0; e < 8; ++e) { float d0 = loadAcc[e] - m; v += d0 * d0; }
        v *= (1.0f / 7.0f);   // ddof=1
        out[(size_t)N_TOK * DMODEL] = W_LOAD_C * v / (m * m);
    }
}

extern "C" void kernel_launch(void* const* d_in, const int* in_sizes, int n_in,
                              void* d_out, int out_size, void* d_ws, size_t ws_size,
                              hipStream_t stream) {
    const float* x       = (const float*)d_in[0];
    const float* noise   = (const float*)d_in[1];
    const float* gate_w  = (const float*)d_in[2];
    const float* noise_w = (const float*)d_in[3];
    const float* w1      = (const float*)d_in[4];
    const float* b1      = (const float*)d_in[5];
    const float* w2      = (const float*)d_in[6];
    const float* b2      = (const float*)d_in[7];
    float* out = (float*)d_out;
    char* ws = (char*)d_ws;

    int*      cnt     = (int*)(ws + 0);
    float*    loadAcc = (float*)(ws + 256);
    int*      ebase   = (int*)(ws + 512);
    int*      be      = (int*)(ws + 1024);        // 264 ints
    int*      brow    = (int*)(ws + 3072);        // 264 ints
    int*      rowlist = (int*)(ws + 8192);        // 256 KiB
    int*      tpos0   = (int*)(ws + 270336);      // 64 KiB each
    int*      tpos1   = (int*)(ws + 335872);
    float*    tw0     = (float*)(ws + 401408);
    float*    tw1     = (float*)(ws + 466944);
    float*    slotw   = (float*)(ws + 532480);    // 256 KiB (fallback only)
    uint16_t* xb      = (uint16_t*)(ws + 794624); // 32 MiB
    uint16_t* w1t     = (uint16_t*)(ws + 34349056);  // 64 MiB
    uint16_t* w2t     = (uint16_t*)(ws + 101457920); // 64 MiB
    uint16_t* h       = (uint16_t*)(ws + 168566784); // 264*128 x 4096 bf16
    const size_t HOFF = 168566784ull;
    const size_t HSZ  = (size_t)MAXB2 * 128 * DFF * 2;     // 276,824,064
    uint16_t* y2      = (uint16_t*)(ws + HOFF + HSZ);      // packed y+b2 bf16
    const size_t Y2SZ = (size_t)MAXB2 * 128 * DMODEL * 2;  // 69,206,016
    const bool gatherPath = ws_size >= HOFF + HSZ + Y2SZ;

    hipMemsetAsync(ws, 0, 4096, stream);

    gating_kernel<<<2048, 512, 0, stream>>>(x, noise, gate_w, noise_w,
                                            cnt, loadAcc, rowlist, slotw,
                                            tpos0, tpos1, tw0, tw1, xb);
    scan_kernel<<<1, 64, 0, stream>>>(cnt, be, brow, ebase);
    transpose_w_kernel<<<dim3(128, 32, 8), 256, 0, stream>>>(w1, w1t, 1024, 4096);
    transpose_w_kernel<<<dim3(32, 128, 8), 256, 0, stream>>>(w2, w2t, 4096, 1024);
    finalize_kernel<<<1, 64, 0, stream>>>(loadAcc, out);

    if (gatherPath) {
        gemm_kernel<1024, 1, 1, 0, 1><<<dim3(32, MAXB2), 256, 0, stream>>>(
            xb, w1t, rowlist, slotw, cnt, be, brow, b1, h, nullptr, DFF, 0);
        gemm_kernel<4096, 0, 0, 0, 0><<<dim3(8, MAXB2), 256, 0, stream>>>(
            h, w2t, rowlist, slotw, cnt, be, brow, b2, y2, nullptr, DMODEL, 0);
        combine_kernel<<<4096, 256, 0, stream>>>(y2, tpos0, tpos1, tw0, tw1,
                                                 ebase, out);
    } else {
        // fallback: atomic combine (chunked if h doesn't fit)
        hipMemsetAsync(d_out, 0, (size_t)out_size * sizeof(float), stream);
        size_t avail = (ws_size > HOFF) ? ws_size - HOFF : 0;
        int nch = 8, bpc = (MAXB2 + 7) / 8;
        for (int c = 1; c <= 8; c <<= 1) {
            int b = (MAXB2 + c - 1) / c;
            if ((size_t)b * 128 * DFF * 2 <= avail) { nch = c; bpc = b; break; }
        }
        for (int c = 0; c < nch; ++c) {
            int bo = c * bpc;
            if (bo >= MAXB2) break;
            gemm_kernel<1024, 1, 1, 0, 1><<<dim3(32, bpc), 256, 0, stream>>>(
                xb, w1t, rowlist, slotw, cnt, be, brow, b1, h, nullptr, DFF, bo);
            gemm_kernel<4096, 0, 0, 1, 0><<<dim3(8, bpc), 256, 0, stream>>>(
                h, w2t, rowlist, slotw, cnt, be, brow, b2, nullptr, out, DMODEL, bo);
        }
    }
}

// Round 14
// 1019.357 us; speedup vs baseline: 1.3021x; 1.3021x over previous
//
#include <hip/hip_runtime.h>
#include <stdint.h>

#define N_TOK   16384
#define DMODEL  1024
#define NEXP    8
#define DFF     4096
#define CAP     8192
#define MAXB2   264          // 32768/128 + 8 (per-expert 128-row padding)
#define W_LOAD_C 0.01f

typedef __attribute__((ext_vector_type(8))) short short8;
typedef __attribute__((ext_vector_type(4))) float f32x4;

__device__ __forceinline__ uint16_t f2bf(float f) {
    uint32_t u = __float_as_uint(f);
    uint32_t r = u + 0x7fffu + ((u >> 16) & 1u);
    return (uint16_t)(r >> 16);
}
__device__ __forceinline__ float bf2f(uint16_t u) {
    return __uint_as_float((uint32_t)u << 16);
}

__device__ __forceinline__ float gelu_tanh(float v) {
    float u = 0.7978845608028654f * (v + 0.044715f * v * v * v);
    float ex = __expf(2.0f * u);
    float th = 1.0f - 2.0f / (ex + 1.0f);
    return 0.5f * v * (1.0f + th);
}

__device__ __forceinline__ void glds16(const uint16_t* g, uint16_t* l) {
    __builtin_amdgcn_global_load_lds(
        (const __attribute__((address_space(1))) void*)g,
        (__attribute__((address_space(3))) void*)l, 16, 0, 0);
}

// ---------------- gating + routing + load-loss + fused x->bf16 ----------------
// Dot-product code kept bitwise-identical to the passing rounds.
__global__ __launch_bounds__(512) void gating_kernel(
    const float* __restrict__ x, const float* __restrict__ noise,
    const float* __restrict__ gate_w, const float* __restrict__ noise_w,
    int* __restrict__ cnt, float* __restrict__ loadAcc,
    int* __restrict__ rowlist, float* __restrict__ slotw,
    int* __restrict__ tpos0, int* __restrict__ tpos1,
    float* __restrict__ tw0, float* __restrict__ tw1,
    uint16_t* __restrict__ xb)
{
    __shared__ float lp[8][8];
    __shared__ int   se1[8], se2[8];
    __shared__ float sw1[8], sw2[8];

    const int lane = threadIdx.x & 63;
    const int wid  = threadIdx.x >> 6;
    const int t = blockIdx.x * 8 + wid;

    const float* xr = x + (size_t)t * DMODEL;
    uint16_t* xbr = xb + (size_t)t * DMODEL;
    float ag[8] = {0,0,0,0,0,0,0,0};
    float an[8] = {0,0,0,0,0,0,0,0};
    for (int j = 0; j < 16; ++j) {
        int idx = j * 64 + lane;
        float xv = xr[idx];
        xbr[idx] = f2bf(xv);
        const float4* gp  = (const float4*)(gate_w  + idx * 8);
        const float4* np_ = (const float4*)(noise_w + idx * 8);
        float4 g0 = gp[0], g1 = gp[1];
        float4 n0 = np_[0], n1 = np_[1];
        ag[0] += xv * g0.x; ag[1] += xv * g0.y; ag[2] += xv * g0.z; ag[3] += xv * g0.w;
        ag[4] += xv * g1.x; ag[5] += xv * g1.y; ag[6] += xv * g1.z; ag[7] += xv * g1.w;
        an[0] += xv * n0.x; an[1] += xv * n0.y; an[2] += xv * n0.z; an[3] += xv * n0.w;
        an[4] += xv * n1.x; an[5] += xv * n1.y; an[6] += xv * n1.z; an[7] += xv * n1.w;
    }
    #pragma unroll
    for (int m = 32; m >= 1; m >>= 1) {
        #pragma unroll
        for (int e = 0; e < 8; ++e) {
            ag[e] += __shfl_xor(ag[e], m, 64);
            an[e] += __shfl_xor(an[e], m, 64);
        }
    }
    float logit[8], sdv[8];
    #pragma unroll
    for (int e = 0; e < 8; ++e) {
        float a = an[e];
        float sp = (a > 20.0f) ? a : log1pf(expf(a));
        sdv[e] = sp;
        logit[e] = ag[e] + noise[(size_t)t * 8 + e] * sp;
    }
    float v1 = -1e30f, v2 = -1e30f, v3 = -1e30f; int i1 = 0, i2 = 0;
    #pragma unroll
    for (int e = 0; e < 8; ++e) {
        float v = logit[e];
        if (v > v1)      { v3 = v2; v2 = v1; i2 = i1; v1 = v; i1 = e; }
        else if (v > v2) { v3 = v2; v2 = v; i2 = e; }
        else if (v > v3) { v3 = v; }
    }
    if (lane < 8) {
        float kth = (lane == i1 || lane == i2) ? v3 : v2;
        float z = (logit[lane] - kth) / sdv[lane];
        lp[wid][lane] = 0.5f * erfcf(-z * 0.70710678118654752440f);
    }
    if (lane == 0) {
        float e2 = expf(v2 - v1);
        float inv = 1.0f / (1.0f + e2);
        se1[wid] = i1; se2[wid] = i2;
        sw1[wid] = inv; sw2[wid] = e2 * inv;
        tw0[t] = inv; tw1[t] = e2 * inv;
    }
    __syncthreads();
    if (threadIdx.x < 8) {
        int e = threadIdx.x;
        float s = 0.f;
        #pragma unroll
        for (int w = 0; w < 8; ++w) s += lp[w][e];
        atomicAdd(&loadAcc[e], s);
        int m = 0;
        #pragma unroll
        for (int w = 0; w < 8; ++w) m += (se1[w] == e) + (se2[w] == e);
        if (m > 0) {
            int b = atomicAdd(&cnt[e], m);
            #pragma unroll
            for (int w = 0; w < 8; ++w) {
                int tok = blockIdx.x * 8 + w;
                if (se1[w] == e) {
                    if (b < CAP) { rowlist[e * CAP + b] = tok; slotw[e * CAP + b] = sw1[w]; }
                    tpos0[tok] = e * 32768 + b;
                    b++;
                }
                if (se2[w] == e) {
                    if (b < CAP) { rowlist[e * CAP + b] = tok; slotw[e * CAP + b] = sw2[w]; }
                    tpos1[tok] = e * 32768 + b;
                    b++;
                }
            }
        }
    }
}

// ---------------- block map scan: expert/row per 128-row packed block ----------------
__global__ void scan_kernel(const int* __restrict__ cnt,
                            int* __restrict__ be, int* __restrict__ brow,
                            int* __restrict__ ebase)
{
    if (threadIdx.x == 0 && blockIdx.x == 0) {
        int idx = 0;
        for (int e = 0; e < NEXP; ++e) {
            int ce = cnt[e]; if (ce > CAP) ce = CAP;
            int nb = (ce + 127) >> 7;
            ebase[e] = idx * 128;   // packed base row of expert e
            for (int k = 0; k < nb; ++k) { be[idx] = e; brow[idx] = k * 128; idx++; }
        }
        for (; idx < MAXB2; ++idx) { be[idx] = -1; brow[idx] = 0; }
    }
}

// ---------------- per-expert transpose f32 [R][C] -> bf16 [C][R] ----------------
__global__ __launch_bounds__(256) void transpose_w_kernel(
    const float* __restrict__ src, uint16_t* __restrict__ dst, int R, int Cc)
{
    __shared__ float tile[32][33];
    const float* s = src + (size_t)blockIdx.z * R * Cc;
    uint16_t*    d = dst + (size_t)blockIdx.z * R * Cc;
    int c0 = blockIdx.x * 32, r0 = blockIdx.y * 32;
    int tx = threadIdx.x & 31, ty = threadIdx.x >> 5;
    #pragma unroll
    for (int rr = ty; rr < 32; rr += 8)
        tile[rr][tx] = s[(size_t)(r0 + rr) * Cc + c0 + tx];
    __syncthreads();
    #pragma unroll
    for (int rr = ty; rr < 32; rr += 8)
        d[(size_t)(c0 + rr) * R + r0 + tx] = f2bf(tile[tx][rr]);
}

// ---------------- GEMM: 128x128 tile, BK=32, 4 waves, 3 blocks/CU ----------------
// r14 = r11 structure + r13's fix (a) only, NT store REVERTED.
// r13 post-mortem: unroll-by-3 (a) cut VALUBusy 38.7->18.9% as predicted; the
// NT h-store (b) quadrupled WRITE_SIZE (266MB->1.01GB == 16B NT stores hitting
// HBM as 64B transactions, bypassing L2 write-coalescing) -- reverted.
template<int KTOT, int GATHER, int GELU, int ATOMIC>
__global__ __launch_bounds__(256, 3) void gemm_kernel(
    const uint16_t* __restrict__ Abase,
    const uint16_t* __restrict__ Bfull,
    const int*      __restrict__ rowlist,
    const float*    __restrict__ slotw,
    const int*      __restrict__ cnt,
    const int*      __restrict__ be,
    const int*      __restrict__ brow,
    const float*    __restrict__ biasFull,
    uint16_t*       __restrict__ OutBf,
    float*          __restrict__ OutF,
    int ncols, int bo)
{
    // 48 KiB: 3 ring slots x (A 8KB: subtiles 0..7 | B 8KB @ +8192).
    // Subtile = 16 rows x 32 K bf16 = 1024 B. Epilogue reuses ring as
    // 128x136 u16 arena. lsm FIRST so LDS base = 0 (imm folding).
    __shared__ uint16_t lsm[24576];
    __shared__ int   lT[128];
    __shared__ float lW[128];

    // bijective XCD swizzle (m204)
    const int nwg  = gridDim.x * gridDim.y;
    const int flat = blockIdx.y * gridDim.x + blockIdx.x;
    const int xcd = flat & 7, sid = flat >> 3;
    const int q = nwg >> 3, r8_ = nwg & 7;
    const int f2 = (xcd < r8_ ? xcd * (q + 1) : r8_ * (q + 1) + (xcd - r8_) * q) + sid;
    const int nx  = f2 % gridDim.x;
    const int rbi = f2 / gridDim.x;

    const int rb = rbi + bo;
    if (rb >= MAXB2) return;
    const int e = be[rb];
    if (e < 0) return;
    const int row0 = brow[rb];
    int ce = cnt[e]; if (ce > CAP) ce = CAP;
    const int n0 = nx * 128;

    const int t    = threadIdx.x;
    const int lane = t & 63, wid = t >> 6;          // 4 waves
    const int fr = lane & 15, ks = lane >> 4;
    const int wr = wid >> 1, wc = wid & 1;          // 2(M) x 2(N) wave grid

    if (ATOMIC) {
        if (t < 128) {
            int rr = row0 + t;
            int rc = (rr < ce) ? rr : (ce - 1);
            lT[t] = rowlist[e * CAP + rc];
            lW[t] = (rr < ce) ? slotw[e * CAP + rr] : 0.0f;
        }
        __syncthreads();
    }

    // ---- staging: instr j (0,1) fills subtile wid+4j; lane l covers bytes
    // [l*16, l*16+16). st_16x32 inverse swizzle on the SOURCE granule.
    const uint16_t* Bp = Bfull + (size_t)e * ncols * KTOT;
    const int rsub = lane >> 2;
    const int kof  = ((lane & 3) ^ (((lane >> 5) & 1) << 1)) * 8;
    const int rowT0 = wid * 16 + rsub;          // subtiles 0..3
    const int rowT1 = 64 + wid * 16 + rsub;     // subtiles 4..7
    size_t gr0, gr1;
    if (GATHER) {
        int r0c = row0 + rowT0; r0c = (r0c < ce) ? r0c : (ce - 1);
        int r1c = row0 + rowT1; r1c = (r1c < ce) ? r1c : (ce - 1);
        gr0 = (size_t)rowlist[e * CAP + r0c];
        gr1 = (size_t)rowlist[e * CAP + r1c];
    } else {
        gr0 = (size_t)rbi * 128 + rowT0;
        gr1 = (size_t)rbi * 128 + rowT1;
    }
    const uint16_t* pA0 = Abase + gr0 * KTOT + kof;
    const uint16_t* pA1 = Abase + gr1 * KTOT + kof;
    const uint16_t* pB0 = Bp + (size_t)(n0 + rowT0) * KTOT + kof;
    const uint16_t* pB1 = Bp + (size_t)(n0 + rowT1) * KTOT + kof;
    const int dA0 = wid * 1024 + lane * 16;     // LDS byte offsets (linear dest)
    const int dA1 = (4 + wid) * 1024 + lane * 16;
    const int dB0 = 8192 + dA0;
    const int dB1 = 8192 + dA1;

    // ---- ds_read byte offsets within slot 0 (swizzled; conflicts = 0) ----
    const int sw = (ks * 16) ^ ((fr >> 3) << 5);
    int aOff[4], bOff[4];
    #pragma unroll
    for (int m = 0; m < 4; ++m) aOff[m] = (wr * 4 + m) * 1024 + fr * 64 + sw;
    #pragma unroll
    for (int n = 0; n < 4; ++n) bOff[n] = 8192 + (wc * 4 + n) * 1024 + fr * 64 + sw;

    f32x4 acc[4][4];
    #pragma unroll
    for (int a = 0; a < 4; ++a)
        #pragma unroll
        for (int b = 0; b < 4; ++b) acc[a][b] = (f32x4){0.f, 0.f, 0.f, 0.f};

    constexpr int NKT = KTOT / 32;
    char* lsb = (char*)lsm;

    // prologue: stage K-tiles 0,1 into slots 0,1; wait tile 0 (4 in flight)
    #pragma unroll
    for (int p = 0; p < 2; ++p) {
        char* db = lsb + p * 16384;
        glds16(pA0 + p * 32, (uint16_t*)(db + dA0));
        glds16(pA1 + p * 32, (uint16_t*)(db + dA1));
        glds16(pB0 + p * 32, (uint16_t*)(db + dB0));
        glds16(pB1 + p * 32, (uint16_t*)(db + dB1));
    }
    asm volatile("s_waitcnt vmcnt(4)" ::: "memory");
    __builtin_amdgcn_s_barrier();
    asm volatile("" ::: "memory");

    // K-loop unrolled by 3: RS_ = read slot (compile-time), SS_ = stage slot,
    // SOFF_ = stage element offset from the triple-base pointers.
#define K_STEP(KT_, RS_, SS_, SOFF_)                                         \
  {                                                                          \
    if ((KT_) + 2 < NKT) {                                                   \
      glds16(pA0 + (SOFF_), (uint16_t*)(lsb + (SS_) * 16384 + dA0));         \
      glds16(pA1 + (SOFF_), (uint16_t*)(lsb + (SS_) * 16384 + dA1));         \
      glds16(pB0 + (SOFF_), (uint16_t*)(lsb + (SS_) * 16384 + dB0));         \
      glds16(pB1 + (SOFF_), (uint16_t*)(lsb + (SS_) * 16384 + dB1));         \
    }                                                                        \
    short8 af[4], bf[4];                                                     \
    _Pragma("unroll")                                                        \
    for (int m = 0; m < 4; ++m)                                              \
      af[m] = *(const short8*)(lsb + (RS_) * 16384 + aOff[m]);               \
    _Pragma("unroll")                                                        \
    for (int n = 0; n < 4; ++n)                                              \
      bf[n] = *(const short8*)(lsb + (RS_) * 16384 + bOff[n]);               \
    __builtin_amdgcn_s_setprio(1);                                           \
    _Pragma("unroll")                                                        \
    for (int m = 0; m < 4; ++m)                                              \
      _Pragma("unroll")                                                      \
      for (int n = 0; n < 4; ++n)                                            \
        acc[m][n] = __builtin_amdgcn_mfma_f32_16x16x32_bf16(                 \
            af[m], bf[n], acc[m][n], 0, 0, 0);                               \
    __builtin_amdgcn_s_setprio(0);                                           \
    {                                                                        \
      const int rem_ = NKT - 1 - (KT_);                                      \
      if (rem_ >= 2)      asm volatile("s_waitcnt vmcnt(4)" ::: "memory");   \
      else if (rem_ == 1) asm volatile("s_waitcnt vmcnt(0)" ::: "memory");   \
    }                                                                        \
    asm volatile("" ::: "memory");                                           \
    __builtin_amdgcn_s_barrier();                                            \
    asm volatile("" ::: "memory");                                           \
  }

    for (int ktb = 0; ktb < NKT; ktb += 3) {
        K_STEP(ktb,     0, 2, 64);
        if (ktb + 1 < NKT) K_STEP(ktb + 1, 1, 0, 96);
        if (ktb + 2 < NKT) K_STEP(ktb + 2, 2, 1, 128);
        pA0 += 96; pA1 += 96; pB0 += 96; pB1 += 96;
    }
#undef K_STEP

    // ---- epilogue: D mapping col = lane&15, row = (lane>>4)*4 + j [m89/m91] ----
    const float* bias = biasFull + (size_t)e * ncols;
    if (ATOMIC) {
        #pragma unroll
        for (int mi = 0; mi < 4; ++mi) {
            const int rbase = wr * 64 + mi * 16 + ks * 4;
            #pragma unroll
            for (int ni = 0; ni < 4; ++ni) {
                const int c = n0 + wc * 64 + ni * 16 + fr;
                const float bv = bias[c];
                #pragma unroll
                for (int j = 0; j < 4; ++j) {
                    const int rl = rbase + j;
                    if (row0 + rl < ce) {
                        float v = acc[mi][ni][j] + bv;
                        atomicAdd(&OutF[(size_t)lT[rl] * DMODEL + c], lW[rl] * v);
                    }
                }
            }
        }
    } else {
        // staged, coalesced stores via the LDS arena (128 x 128 u16, stride 136)
        __syncthreads();
        #pragma unroll
        for (int mi = 0; mi < 4; ++mi) {
            #pragma unroll
            for (int ni = 0; ni < 4; ++ni) {
                const int cl = wc * 64 + ni * 16 + fr;
                const float bv = bias[n0 + cl];
                #pragma unroll
                for (int j = 0; j < 4; ++j) {
                    float v = acc[mi][ni][j] + bv;
                    if (GELU) v = gelu_tanh(v);
                    const int rl = wr * 64 + mi * 16 + ks * 4 + j;
                    lsm[rl * 136 + cl] = f2bf(v);
                }
            }
        }
        __syncthreads();
        const int r2 = t >> 1, hcol = (t & 1) * 64;
        uint16_t* gp = OutBf + ((size_t)rbi * 128 + r2) * ncols + n0 + hcol;
        #pragma unroll
        for (int j2 = 0; j2 < 8; ++j2) {
            short8 v = *(const short8*)&lsm[r2 * 136 + hcol + j2 * 8];
            *(short8*)(gp + j2 * 8) = v;
        }
    }
}

// ---------------- combine: out[t] = w0*y2[p0] + w1*y2[p1] (gather, no atomics) ----
__global__ __launch_bounds__(256) void combine_kernel(
    const uint16_t* __restrict__ y2,
    const int* __restrict__ tpos0, const int* __restrict__ tpos1,
    const float* __restrict__ tw0, const float* __restrict__ tw1,
    const int* __restrict__ ebase, float* __restrict__ out)
{
    const int wid = threadIdx.x >> 6, lane = threadIdx.x & 63;
    const int t = blockIdx.x * 4 + wid;
    const int p0 = tpos0[t], p1 = tpos1[t];
    const int e0 = p0 >> 15, s0 = p0 & 32767;
    const int e1 = p1 >> 15, s1 = p1 & 32767;
    const bool v0 = s0 < CAP, v1 = s1 < CAP;
    const float w0 = v0 ? tw0[t] : 0.0f;
    const float w1 = v1 ? tw1[t] : 0.0f;
    const uint16_t* r0p = y2 + ((size_t)ebase[e0] + (v0 ? s0 : 0)) * DMODEL;
    const uint16_t* r1p = y2 + ((size_t)ebase[e1] + (v1 ? s1 : 0)) * DMODEL;
    float* op = out + (size_t)t * DMODEL;
    #pragma unroll
    for (int half = 0; half < 2; ++half) {
        const int off = half * 512 + lane * 8;
        short8 a = *(const short8*)(r0p + off);
        short8 b = *(const short8*)(r1p + off);
        float4 o0, o1;
        o0.x = w0 * bf2f((uint16_t)a[0]) + w1 * bf2f((uint16_t)b[0]);
        o0.y = w0 * bf2f((uint16_t)a[1]) + w1 * bf2f((uint16_t)b[1]);
        o0.z = w0 * bf2f((uint16_t)a[2]) + w1 * bf2f((uint16_t)b[2]);
        o0.w = w0 * bf2f((uint16_t)a[3]) + w1 * bf2f((uint16_t)b[3]);
        o1.x = w0 * bf2f((uint16_t)a[4]) + w1 * bf2f((uint16_t)b[4]);
        o1.y = w0 * bf2f((uint16_t)a[5]) + w1 * bf2f((uint16_t)b[5]);
        o1.z = w0 * bf2f((uint16_t)a[6]) + w1 * bf2f((uint16_t)b[6]);
        o1.w = w0 * bf2f((uint16_t)a[7]) + w1 * bf2f((uint16_t)b[7]);
        *(float4*)(op + off)     = o0;
        *(float4*)(op + off + 4) = o1;
    }
}

// ---------------- load-loss finalize ----------------
__global__ void finalize_kernel(const float* __restrict__ loadAcc, float* __restrict__ out) {
    if (threadIdx.x == 0) {
        float m = 0.f;
        #pragma unroll
        for (int e = 0; e < 8; ++e) m += loadAcc[e];
        m *= 0.125f;
        float v = 0.f;
        #pragma unroll
        for (int e = 0; e < 8; ++e) { float d0 = loadAcc[e] - m; v += d0 * d0; }
        v *= (1.0f / 7.0f);   // ddof=1
        out[(size_t)N_TOK * DMODEL] = W_LOAD_C * v / (m * m);
    }
}

extern "C" void kernel_launch(void* const* d_in, const int* in_sizes, int n_in,
                              void* d_out, int out_size, void* d_ws, size_t ws_size,
                              hipStream_t stream) {
    const float* x       = (const float*)d_in[0];
    const float* noise   = (const float*)d_in[1];
    const float* gate_w  = (const float*)d_in[2];
    const float* noise_w = (const float*)d_in[3];
    const float* w1      = (const float*)d_in[4];
    const float* b1      = (const float*)d_in[5];
    const float* w2      = (const float*)d_in[6];
    const float* b2      = (const float*)d_in[7];
    float* out = (float*)d_out;
    char* ws = (char*)d_ws;

    int*      cnt     = (int*)(ws + 0);
    float*    loadAcc = (float*)(ws + 256);
    int*      ebase   = (int*)(ws + 512);
    int*      be      = (int*)(ws + 1024);        // 264 ints
    int*      brow    = (int*)(ws + 3072);        // 264 ints
    int*      rowlist = (int*)(ws + 8192);        // 256 KiB
    int*      tpos0   = (int*)(ws + 270336);      // 64 KiB each
    int*      tpos1   = (int*)(ws + 335872);
    float*    tw0     = (float*)(ws + 401408);
    float*    tw1     = (float*)(ws + 466944);
    float*    slotw   = (float*)(ws + 532480);    // 256 KiB (fallback only)
    uint16_t* xb      = (uint16_t*)(ws + 794624); // 32 MiB
    uint16_t* w1t     = (uint16_t*)(ws + 34349056);  // 64 MiB
    uint16_t* w2t     = (uint16_t*)(ws + 101457920); // 64 MiB
    uint16_t* h       = (uint16_t*)(ws + 168566784); // 264*128 x 4096 bf16
    const size_t HOFF = 168566784ull;
    const size_t HSZ  = (size_t)MAXB2 * 128 * DFF * 2;     // 276,824,064
    uint16_t* y2      = (uint16_t*)(ws + HOFF + HSZ);      // packed y+b2 bf16
    const size_t Y2SZ = (size_t)MAXB2 * 128 * DMODEL * 2;  // 69,206,016
    const bool gatherPath = ws_size >= HOFF + HSZ + Y2SZ;

    hipMemsetAsync(ws, 0, 4096, stream);

    gating_kernel<<<2048, 512, 0, stream>>>(x, noise, gate_w, noise_w,
                                            cnt, loadAcc, rowlist, slotw,
                                            tpos0, tpos1, tw0, tw1, xb);
    scan_kernel<<<1, 64, 0, stream>>>(cnt, be, brow, ebase);
    transpose_w_kernel<<<dim3(128, 32, 8), 256, 0, stream>>>(w1, w1t, 1024, 4096);
    transpose_w_kernel<<<dim3(32, 128, 8), 256, 0, stream>>>(w2, w2t, 4096, 1024);
    finalize_kernel<<<1, 64, 0, stream>>>(loadAcc, out);

    if (gatherPath) {
        gemm_kernel<1024, 1, 1, 0><<<dim3(32, MAXB2), 256, 0, stream>>>(
            xb, w1t, rowlist, slotw, cnt, be, brow, b1, h, nullptr, DFF, 0);
        gemm_kernel<4096, 0, 0, 0><<<dim3(8, MAXB2), 256, 0, stream>>>(
            h, w2t, rowlist, slotw, cnt, be, brow, b2, y2, nullptr, DMODEL, 0);
        combine_kernel<<<4096, 256, 0, stream>>>(y2, tpos0, tpos1, tw0, tw1,
                                                 ebase, out);
    } else {
        // fallback: atomic combine (chunked if h doesn't fit)
        hipMemsetAsync(d_out, 0, (size_t)out_size * sizeof(float), stream);
        size_t avail = (ws_size > HOFF) ? ws_size - HOFF : 0;
        int nch = 8, bpc = (MAXB2 + 7) / 8;
        for (int c = 1; c <= 8; c <<= 1) {
            int b = (MAXB2 + c - 1) / c;
            if ((size_t)b * 128 * DFF * 2 <= avail) { nch = c; bpc = b; break; }
        }
        for (int c = 0; c < nch; ++c) {
            int bo = c * bpc;
            if (bo >= MAXB2) break;
            gemm_kernel<1024, 1, 1, 0><<<dim3(32, bpc), 256, 0, stream>>>(
                xb, w1t, rowlist, slotw, cnt, be, brow, b1, h, nullptr, DFF, bo);
            gemm_kernel<4096, 0, 0, 1><<<dim3(8, bpc), 256, 0, stream>>>(
                h, w2t, rowlist, slotw, cnt, be, brow, b2, nullptr, out, DMODEL, bo);
        }
    }
}

// Round 15
// 972.049 us; speedup vs baseline: 1.3654x; 1.0487x over previous
//
#include <hip/hip_runtime.h>
#include <stdint.h>

#define N_TOK   16384
#define DMODEL  1024
#define NEXP    8
#define DFF     4096
#define CAP     8192
#define MAXB2   264          // 32768/128 + 8 (per-expert 128-row padding)
#define W_LOAD_C 0.01f

typedef __attribute__((ext_vector_type(8))) short short8;
typedef __attribute__((ext_vector_type(4))) float f32x4;

__device__ __forceinline__ uint16_t f2bf(float f) {
    uint32_t u = __float_as_uint(f);
    uint32_t r = u + 0x7fffu + ((u >> 16) & 1u);
    return (uint16_t)(r >> 16);
}
__device__ __forceinline__ float bf2f(uint16_t u) {
    return __uint_as_float((uint32_t)u << 16);
}

__device__ __forceinline__ float gelu_tanh(float v) {
    float u = 0.7978845608028654f * (v + 0.044715f * v * v * v);
    float ex = __expf(2.0f * u);
    float th = 1.0f - 2.0f / (ex + 1.0f);
    return 0.5f * v * (1.0f + th);
}

__device__ __forceinline__ void glds16(const uint16_t* g, uint16_t* l) {
    __builtin_amdgcn_global_load_lds(
        (const __attribute__((address_space(1))) void*)g,
        (__attribute__((address_space(3))) void*)l, 16, 0, 0);
}

// ---------------- gating + routing + load-loss + fused x->bf16 ----------------
// Dot-product code kept bitwise-identical to the passing rounds.
__global__ __launch_bounds__(512) void gating_kernel(
    const float* __restrict__ x, const float* __restrict__ noise,
    const float* __restrict__ gate_w, const float* __restrict__ noise_w,
    int* __restrict__ cnt, float* __restrict__ loadAcc,
    int* __restrict__ rowlist, float* __restrict__ slotw,
    int* __restrict__ tpos0, int* __restrict__ tpos1,
    float* __restrict__ tw0, float* __restrict__ tw1,
    uint16_t* __restrict__ xb)
{
    __shared__ float lp[8][8];
    __shared__ int   se1[8], se2[8];
    __shared__ float sw1[8], sw2[8];

    const int lane = threadIdx.x & 63;
    const int wid  = threadIdx.x >> 6;
    const int t = blockIdx.x * 8 + wid;

    const float* xr = x + (size_t)t * DMODEL;
    uint16_t* xbr = xb + (size_t)t * DMODEL;
    float ag[8] = {0,0,0,0,0,0,0,0};
    float an[8] = {0,0,0,0,0,0,0,0};
    for (int j = 0; j < 16; ++j) {
        int idx = j * 64 + lane;
        float xv = xr[idx];
        xbr[idx] = f2bf(xv);
        const float4* gp  = (const float4*)(gate_w  + idx * 8);
        const float4* np_ = (const float4*)(noise_w + idx * 8);
        float4 g0 = gp[0], g1 = gp[1];
        float4 n0 = np_[0], n1 = np_[1];
        ag[0] += xv * g0.x; ag[1] += xv * g0.y; ag[2] += xv * g0.z; ag[3] += xv * g0.w;
        ag[4] += xv * g1.x; ag[5] += xv * g1.y; ag[6] += xv * g1.z; ag[7] += xv * g1.w;
        an[0] += xv * n0.x; an[1] += xv * n0.y; an[2] += xv * n0.z; an[3] += xv * n0.w;
        an[4] += xv * n1.x; an[5] += xv * n1.y; an[6] += xv * n1.z; an[7] += xv * n1.w;
    }
    #pragma unroll
    for (int m = 32; m >= 1; m >>= 1) {
        #pragma unroll
        for (int e = 0; e < 8; ++e) {
            ag[e] += __shfl_xor(ag[e], m, 64);
            an[e] += __shfl_xor(an[e], m, 64);
        }
    }
    float logit[8], sdv[8];
    #pragma unroll
    for (int e = 0; e < 8; ++e) {
        float a = an[e];
        float sp = (a > 20.0f) ? a : log1pf(expf(a));
        sdv[e] = sp;
        logit[e] = ag[e] + noise[(size_t)t * 8 + e] * sp;
    }
    float v1 = -1e30f, v2 = -1e30f, v3 = -1e30f; int i1 = 0, i2 = 0;
    #pragma unroll
    for (int e = 0; e < 8; ++e) {
        float v = logit[e];
        if (v > v1)      { v3 = v2; v2 = v1; i2 = i1; v1 = v; i1 = e; }
        else if (v > v2) { v3 = v2; v2 = v; i2 = e; }
        else if (v > v3) { v3 = v; }
    }
    if (lane < 8) {
        float kth = (lane == i1 || lane == i2) ? v3 : v2;
        float z = (logit[lane] - kth) / sdv[lane];
        lp[wid][lane] = 0.5f * erfcf(-z * 0.70710678118654752440f);
    }
    if (lane == 0) {
        float e2 = expf(v2 - v1);
        float inv = 1.0f / (1.0f + e2);
        se1[wid] = i1; se2[wid] = i2;
        sw1[wid] = inv; sw2[wid] = e2 * inv;
        tw0[t] = inv; tw1[t] = e2 * inv;
    }
    __syncthreads();
    if (threadIdx.x < 8) {
        int e = threadIdx.x;
        float s = 0.f;
        #pragma unroll
        for (int w = 0; w < 8; ++w) s += lp[w][e];
        atomicAdd(&loadAcc[e], s);
        int m = 0;
        #pragma unroll
        for (int w = 0; w < 8; ++w) m += (se1[w] == e) + (se2[w] == e);
        if (m > 0) {
            int b = atomicAdd(&cnt[e], m);
            #pragma unroll
            for (int w = 0; w < 8; ++w) {
                int tok = blockIdx.x * 8 + w;
                if (se1[w] == e) {
                    if (b < CAP) { rowlist[e * CAP + b] = tok; slotw[e * CAP + b] = sw1[w]; }
                    tpos0[tok] = e * 32768 + b;
                    b++;
                }
                if (se2[w] == e) {
                    if (b < CAP) { rowlist[e * CAP + b] = tok; slotw[e * CAP + b] = sw2[w]; }
                    tpos1[tok] = e * 32768 + b;
                    b++;
                }
            }
        }
    }
}

// ---------------- block map scan: expert/row per 128-row packed block ----------------
__global__ void scan_kernel(const int* __restrict__ cnt,
                            int* __restrict__ be, int* __restrict__ brow,
                            int* __restrict__ ebase)
{
    if (threadIdx.x == 0 && blockIdx.x == 0) {
        int idx = 0;
        for (int e = 0; e < NEXP; ++e) {
            int ce = cnt[e]; if (ce > CAP) ce = CAP;
            int nb = (ce + 127) >> 7;
            ebase[e] = idx * 128;   // packed base row of expert e
            for (int k = 0; k < nb; ++k) { be[idx] = e; brow[idx] = k * 128; idx++; }
        }
        for (; idx < MAXB2; ++idx) { be[idx] = -1; brow[idx] = 0; }
    }
}

// ---------------- per-expert transpose f32 [R][C] -> bf16 [C][R] ----------------
__global__ __launch_bounds__(256) void transpose_w_kernel(
    const float* __restrict__ src, uint16_t* __restrict__ dst, int R, int Cc)
{
    __shared__ float tile[32][33];
    const float* s = src + (size_t)blockIdx.z * R * Cc;
    uint16_t*    d = dst + (size_t)blockIdx.z * R * Cc;
    int c0 = blockIdx.x * 32, r0 = blockIdx.y * 32;
    int tx = threadIdx.x & 31, ty = threadIdx.x >> 5;
    #pragma unroll
    for (int rr = ty; rr < 32; rr += 8)
        tile[rr][tx] = s[(size_t)(r0 + rr) * Cc + c0 + tx];
    __syncthreads();
    #pragma unroll
    for (int rr = ty; rr < 32; rr += 8)
        d[(size_t)(c0 + rr) * R + r0 + tx] = f2bf(tile[tx][rr]);
}

// ---------------- GEMM: 128x128 tile, BK=32, 4 waves, 3 blocks/CU ----------------
// r15 = r14 + SUPER: 2-D supertiled block mapping for GEMM1. Within an XCD,
// blocks are grouped 4 rbi x 8 nx: L2 working set = 4 A-panels + 8 B-panels
// = 3 MB <= 4 MB, so B panels (w1t) are L2-reused across 4 row-blocks instead
// of re-streamed from thrashed-L3/HBM every row-block (FETCH was 8x
// compulsory). GEMM2 unchanged (its 1 MB panels don't fit a useful supertile).
template<int KTOT, int GATHER, int GELU, int ATOMIC, int SUPER>
__global__ __launch_bounds__(256, 3) void gemm_kernel(
    const uint16_t* __restrict__ Abase,
    const uint16_t* __restrict__ Bfull,
    const int*      __restrict__ rowlist,
    const float*    __restrict__ slotw,
    const int*      __restrict__ cnt,
    const int*      __restrict__ be,
    const int*      __restrict__ brow,
    const float*    __restrict__ biasFull,
    uint16_t*       __restrict__ OutBf,
    float*          __restrict__ OutF,
    int ncols, int bo)
{
    // 48 KiB: 3 ring slots x (A 8KB: subtiles 0..7 | B 8KB @ +8192).
    // Subtile = 16 rows x 32 K bf16 = 1024 B. Epilogue reuses ring as
    // 128x136 u16 arena. lsm FIRST so LDS base = 0 (imm folding).
    __shared__ uint16_t lsm[24576];
    __shared__ int   lT[128];
    __shared__ float lW[128];

    // bijective XCD swizzle (m204) + optional 4x8 supertile decode
    const int nwg  = gridDim.x * gridDim.y;
    const int flat = blockIdx.y * gridDim.x + blockIdx.x;
    const int xcd = flat & 7, sid = flat >> 3;
    const int q = nwg >> 3, r8_ = nwg & 7;
    const int f2 = (xcd < r8_ ? xcd * (q + 1) : r8_ * (q + 1) + (xcd - r8_) * q) + sid;
    int nx, rbi;
    if (SUPER && ((gridDim.y & 3) == 0) && ((gridDim.x & 7) == 0)) {
        const int stW = gridDim.x >> 3;      // supertiles per row (pow2: 4 for x=32)
        const int st  = f2 >> 5, wi = f2 & 31;
        const int stx = st & (stW - 1);
        const int sty = st / stW;
        nx  = (stx << 3) | (wi & 7);
        rbi = (sty << 2) | (wi >> 3);
    } else {
        nx  = f2 % gridDim.x;
        rbi = f2 / gridDim.x;
    }

    const int rb = rbi + bo;
    if (rb >= MAXB2) return;
    const int e = be[rb];
    if (e < 0) return;
    const int row0 = brow[rb];
    int ce = cnt[e]; if (ce > CAP) ce = CAP;
    const int n0 = nx * 128;

    const int t    = threadIdx.x;
    const int lane = t & 63, wid = t >> 6;          // 4 waves
    const int fr = lane & 15, ks = lane >> 4;
    const int wr = wid >> 1, wc = wid & 1;          // 2(M) x 2(N) wave grid

    if (ATOMIC) {
        if (t < 128) {
            int rr = row0 + t;
            int rc = (rr < ce) ? rr : (ce - 1);
            lT[t] = rowlist[e * CAP + rc];
            lW[t] = (rr < ce) ? slotw[e * CAP + rr] : 0.0f;
        }
        __syncthreads();
    }

    // ---- staging: instr j (0,1) fills subtile wid+4j; lane l covers bytes
    // [l*16, l*16+16). st_16x32 inverse swizzle on the SOURCE granule.
    const uint16_t* Bp = Bfull + (size_t)e * ncols * KTOT;
    const int rsub = lane >> 2;
    const int kof  = ((lane & 3) ^ (((lane >> 5) & 1) << 1)) * 8;
    const int rowT0 = wid * 16 + rsub;          // subtiles 0..3
    const int rowT1 = 64 + wid * 16 + rsub;     // subtiles 4..7
    size_t gr0, gr1;
    if (GATHER) {
        int r0c = row0 + rowT0; r0c = (r0c < ce) ? r0c : (ce - 1);
        int r1c = row0 + rowT1; r1c = (r1c < ce) ? r1c : (ce - 1);
        gr0 = (size_t)rowlist[e * CAP + r0c];
        gr1 = (size_t)rowlist[e * CAP + r1c];
    } else {
        gr0 = (size_t)rbi * 128 + rowT0;
        gr1 = (size_t)rbi * 128 + rowT1;
    }
    const uint16_t* pA0 = Abase + gr0 * KTOT + kof;
    const uint16_t* pA1 = Abase + gr1 * KTOT + kof;
    const uint16_t* pB0 = Bp + (size_t)(n0 + rowT0) * KTOT + kof;
    const uint16_t* pB1 = Bp + (size_t)(n0 + rowT1) * KTOT + kof;
    const int dA0 = wid * 1024 + lane * 16;     // LDS byte offsets (linear dest)
    const int dA1 = (4 + wid) * 1024 + lane * 16;
    const int dB0 = 8192 + dA0;
    const int dB1 = 8192 + dA1;

    // ---- ds_read byte offsets within slot 0 (swizzled; conflicts = 0) ----
    const int sw = (ks * 16) ^ ((fr >> 3) << 5);
    int aOff[4], bOff[4];
    #pragma unroll
    for (int m = 0; m < 4; ++m) aOff[m] = (wr * 4 + m) * 1024 + fr * 64 + sw;
    #pragma unroll
    for (int n = 0; n < 4; ++n) bOff[n] = 8192 + (wc * 4 + n) * 1024 + fr * 64 + sw;

    f32x4 acc[4][4];
    #pragma unroll
    for (int a = 0; a < 4; ++a)
        #pragma unroll
        for (int b = 0; b < 4; ++b) acc[a][b] = (f32x4){0.f, 0.f, 0.f, 0.f};

    constexpr int NKT = KTOT / 32;
    char* lsb = (char*)lsm;

    // prologue: stage K-tiles 0,1 into slots 0,1; wait tile 0 (4 in flight)
    #pragma unroll
    for (int p = 0; p < 2; ++p) {
        char* db = lsb + p * 16384;
        glds16(pA0 + p * 32, (uint16_t*)(db + dA0));
        glds16(pA1 + p * 32, (uint16_t*)(db + dA1));
        glds16(pB0 + p * 32, (uint16_t*)(db + dB0));
        glds16(pB1 + p * 32, (uint16_t*)(db + dB1));
    }
    asm volatile("s_waitcnt vmcnt(4)" ::: "memory");
    __builtin_amdgcn_s_barrier();
    asm volatile("" ::: "memory");

    // K-loop unrolled by 3: RS_ = read slot (compile-time), SS_ = stage slot,
    // SOFF_ = stage element offset from the triple-base pointers.
#define K_STEP(KT_, RS_, SS_, SOFF_)                                         \
  {                                                                          \
    if ((KT_) + 2 < NKT) {                                                   \
      glds16(pA0 + (SOFF_), (uint16_t*)(lsb + (SS_) * 16384 + dA0));         \
      glds16(pA1 + (SOFF_), (uint16_t*)(lsb + (SS_) * 16384 + dA1));         \
      glds16(pB0 + (SOFF_), (uint16_t*)(lsb + (SS_) * 16384 + dB0));         \
      glds16(pB1 + (SOFF_), (uint16_t*)(lsb + (SS_) * 16384 + dB1));         \
    }                                                                        \
    short8 af[4], bf[4];                                                     \
    _Pragma("unroll")                                                        \
    for (int m = 0; m < 4; ++m)                                              \
      af[m] = *(const short8*)(lsb + (RS_) * 16384 + aOff[m]);               \
    _Pragma("unroll")                                                        \
    for (int n = 0; n < 4; ++n)                                              \
      bf[n] = *(const short8*)(lsb + (RS_) * 16384 + bOff[n]);               \
    __builtin_amdgcn_s_setprio(1);                                           \
    _Pragma("unroll")                                                        \
    for (int m = 0; m < 4; ++m)                                              \
      _Pragma("unroll")                                                      \
      for (int n = 0; n < 4; ++n)                                            \
        acc[m][n] = __builtin_amdgcn_mfma_f32_16x16x32_bf16(                 \
            af[m], bf[n], acc[m][n], 0, 0, 0);                               \
    __builtin_amdgcn_s_setprio(0);                                           \
    {                                                                        \
      const int rem_ = NKT - 1 - (KT_);                                      \
      if (rem_ >= 2)      asm volatile("s_waitcnt vmcnt(4)" ::: "memory");   \
      else if (rem_ == 1) asm volatile("s_waitcnt vmcnt(0)" ::: "memory");   \
    }                                                                        \
    asm volatile("" ::: "memory");                                           \
    __builtin_amdgcn_s_barrier();                                            \
    asm volatile("" ::: "memory");                                           \
  }

    for (int ktb = 0; ktb < NKT; ktb += 3) {
        K_STEP(ktb,     0, 2, 64);
        if (ktb + 1 < NKT) K_STEP(ktb + 1, 1, 0, 96);
        if (ktb + 2 < NKT) K_STEP(ktb + 2, 2, 1, 128);
        pA0 += 96; pA1 += 96; pB0 += 96; pB1 += 96;
    }
#undef K_STEP

    // ---- epilogue: D mapping col = lane&15, row = (lane>>4)*4 + j [m89/m91] ----
    const float* bias = biasFull + (size_t)e * ncols;
    if (ATOMIC) {
        #pragma unroll
        for (int mi = 0; mi < 4; ++mi) {
            const int rbase = wr * 64 + mi * 16 + ks * 4;
            #pragma unroll
            for (int ni = 0; ni < 4; ++ni) {
                const int c = n0 + wc * 64 + ni * 16 + fr;
                const float bv = bias[c];
                #pragma unroll
                for (int j = 0; j < 4; ++j) {
                    const int rl = rbase + j;
                    if (row0 + rl < ce) {
                        float v = acc[mi][ni][j] + bv;
                        atomicAdd(&OutF[(size_t)lT[rl] * DMODEL + c], lW[rl] * v);
                    }
                }
            }
        }
    } else {
        // staged, coalesced stores via the LDS arena (128 x 128 u16, stride 136)
        __syncthreads();
        #pragma unroll
        for (int mi = 0; mi < 4; ++mi) {
            #pragma unroll
            for (int ni = 0; ni < 4; ++ni) {
                const int cl = wc * 64 + ni * 16 + fr;
                const float bv = bias[n0 + cl];
                #pragma unroll
                for (int j = 0; j < 4; ++j) {
                    float v = acc[mi][ni][j] + bv;
                    if (GELU) v = gelu_tanh(v);
                    const int rl = wr * 64 + mi * 16 + ks * 4 + j;
                    lsm[rl * 136 + cl] = f2bf(v);
                }
            }
        }
        __syncthreads();
        const int r2 = t >> 1, hcol = (t & 1) * 64;
        uint16_t* gp = OutBf + ((size_t)rbi * 128 + r2) * ncols + n0 + hcol;
        #pragma unroll
        for (int j2 = 0; j2 < 8; ++j2) {
            short8 v = *(const short8*)&lsm[r2 * 136 + hcol + j2 * 8];
            *(short8*)(gp + j2 * 8) = v;
        }
    }
}

// ---------------- combine: out[t] = w0*y2[p0] + w1*y2[p1] (gather, no atomics) ----
__global__ __launch_bounds__(256) void combine_kernel(
    const uint16_t* __restrict__ y2,
    const int* __restrict__ tpos0, const int* __restrict__ tpos1,
    const float* __restrict__ tw0, const float* __restrict__ tw1,
    const int* __restrict__ ebase, float* __restrict__ out)
{
    const int wid = threadIdx.x >> 6, lane = threadIdx.x & 63;
    const int t = blockIdx.x * 4 + wid;
    const int p0 = tpos0[t], p1 = tpos1[t];
    const int e0 = p0 >> 15, s0 = p0 & 32767;
    const int e1 = p1 >> 15, s1 = p1 & 32767;
    const bool v0 = s0 < CAP, v1 = s1 < CAP;
    const float w0 = v0 ? tw0[t] : 0.0f;
    const float w1 = v1 ? tw1[t] : 0.0f;
    const uint16_t* r0p = y2 + ((size_t)ebase[e0] + (v0 ? s0 : 0)) * DMODEL;
    const uint16_t* r1p = y2 + ((size_t)ebase[e1] + (v1 ? s1 : 0)) * DMODEL;
    float* op = out + (size_t)t * DMODEL;
    #pragma unroll
    for (int half = 0; half < 2; ++half) {
        const int off = half * 512 + lane * 8;
        short8 a = *(const short8*)(r0p + off);
        short8 b = *(const short8*)(r1p + off);
        float4 o0, o1;
        o0.x = w0 * bf2f((uint16_t)a[0]) + w1 * bf2f((uint16_t)b[0]);
        o0.y = w0 * bf2f((uint16_t)a[1]) + w1 * bf2f((uint16_t)b[1]);
        o0.z = w0 * bf2f((uint16_t)a[2]) + w1 * bf2f((uint16_t)b[2]);
        o0.w = w0 * bf2f((uint16_t)a[3]) + w1 * bf2f((uint16_t)b[3]);
        o1.x = w0 * bf2f((uint16_t)a[4]) + w1 * bf2f((uint16_t)b[4]);
        o1.y = w0 * bf2f((uint16_t)a[5]) + w1 * bf2f((uint16_t)b[5]);
        o1.z = w0 * bf2f((uint16_t)a[6]) + w1 * bf2f((uint16_t)b[6]);
        o1.w = w0 * bf2f((uint16_t)a[7]) + w1 * bf2f((uint16_t)b[7]);
        *(float4*)(op + off)     = o0;
        *(float4*)(op + off + 4) = o1;
    }
}

// ---------------- load-loss finalize ----------------
__global__ void finalize_kernel(const float* __restrict__ loadAcc, float* __restrict__ out) {
    if (threadIdx.x == 0) {
        float m = 0.f;
        #pragma unroll
        for (int e = 0; e < 8; ++e) m += loadAcc[e];
        m *= 0.125f;
        float v = 0.f;
        #pragma unroll
        for (int e = 0; e < 8; ++e) { float d0 = loadAcc[e] - m; v += d0 * d0; }
        v *= (1.0f / 7.0f);   // ddof=1
        out[(size_t)N_TOK * DMODEL] = W_LOAD_C * v / (m * m);
    }
}

extern "C" void kernel_launch(void* const* d_in, const int* in_sizes, int n_in,
                              void* d_out, int out_size, void* d_ws, size_t ws_size,
                              hipStream_t stream) {
    const float* x       = (const float*)d_in[0];
    const float* noise   = (const float*)d_in[1];
    const float* gate_w  = (const float*)d_in[2];
    const float* noise_w = (const float*)d_in[3];
    const float* w1      = (const float*)d_in[4];
    const float* b1      = (const float*)d_in[5];
    const float* w2      = (const float*)d_in[6];
    const float* b2      = (const float*)d_in[7];
    float* out = (float*)d_out;
    char* ws = (char*)d_ws;

    int*      cnt     = (int*)(ws + 0);
    float*    loadAcc = (float*)(ws + 256);
    int*      ebase   = (int*)(ws + 512);
    int*      be      = (int*)(ws + 1024);        // 264 ints
    int*      brow    = (int*)(ws + 3072);        // 264 ints
    int*      rowlist = (int*)(ws + 8192);        // 256 KiB
    int*      tpos0   = (int*)(ws + 270336);      // 64 KiB each
    int*      tpos1   = (int*)(ws + 335872);
    float*    tw0     = (float*)(ws + 401408);
    float*    tw1     = (float*)(ws + 466944);
    float*    slotw   = (float*)(ws + 532480);    // 256 KiB (fallback only)
    uint16_t* xb      = (uint16_t*)(ws + 794624); // 32 MiB
    uint16_t* w1t     = (uint16_t*)(ws + 34349056);  // 64 MiB
    uint16_t* w2t     = (uint16_t*)(ws + 101457920); // 64 MiB
    uint16_t* h       = (uint16_t*)(ws + 168566784); // 264*128 x 4096 bf16
    const size_t HOFF = 168566784ull;
    const size_t HSZ  = (size_t)MAXB2 * 128 * DFF * 2;     // 276,824,064
    uint16_t* y2      = (uint16_t*)(ws + HOFF + HSZ);      // packed y+b2 bf16
    const size_t Y2SZ = (size_t)MAXB2 * 128 * DMODEL * 2;  // 69,206,016
    const bool gatherPath = ws_size >= HOFF + HSZ + Y2SZ;

    hipMemsetAsync(ws, 0, 4096, stream);

    gating_kernel<<<2048, 512, 0, stream>>>(x, noise, gate_w, noise_w,
                                            cnt, loadAcc, rowlist, slotw,
                                            tpos0, tpos1, tw0, tw1, xb);
    scan_kernel<<<1, 64, 0, stream>>>(cnt, be, brow, ebase);
    transpose_w_kernel<<<dim3(128, 32, 8), 256, 0, stream>>>(w1, w1t, 1024, 4096);
    transpose_w_kernel<<<dim3(32, 128, 8), 256, 0, stream>>>(w2, w2t, 4096, 1024);
    finalize_kernel<<<1, 64, 0, stream>>>(loadAcc, out);

    if (gatherPath) {
        gemm_kernel<1024, 1, 1, 0, 1><<<dim3(32, MAXB2), 256, 0, stream>>>(
            xb, w1t, rowlist, slotw, cnt, be, brow, b1, h, nullptr, DFF, 0);
        gemm_kernel<4096, 0, 0, 0, 0><<<dim3(8, MAXB2), 256, 0, stream>>>(
            h, w2t, rowlist, slotw, cnt, be, brow, b2, y2, nullptr, DMODEL, 0);
        combine_kernel<<<4096, 256, 0, stream>>>(y2, tpos0, tpos1, tw0, tw1,
                                                 ebase, out);
    } else {
        // fallback: atomic combine (chunked if h doesn't fit)
        hipMemsetAsync(d_out, 0, (size_t)out_size * sizeof(float), stream);
        size_t avail = (ws_size > HOFF) ? ws_size - HOFF : 0;
        int nch = 8, bpc = (MAXB2 + 7) / 8;
        for (int c = 1; c <= 8; c <<= 1) {
            int b = (MAXB2 + c - 1) / c;
            if ((size_t)b * 128 * DFF * 2 <= avail) { nch = c; bpc = b; break; }
        }
        for (int c = 0; c < nch; ++c) {
            int bo = c * bpc;
            if (bo >= MAXB2) break;
            gemm_kernel<1024, 1, 1, 0, 0><<<dim3(32, bpc), 256, 0, stream>>>(
                xb, w1t, rowlist, slotw, cnt, be, brow, b1, h, nullptr, DFF, bo);
            gemm_kernel<4096, 0, 0, 1, 0><<<dim3(8, bpc), 256, 0, stream>>>(
                h, w2t, rowlist, slotw, cnt, be, brow, b2, nullptr, out, DMODEL, bo);
        }
    }
}

// Round 16
// 948.611 us; speedup vs baseline: 1.3992x; 1.0247x over previous
//
#include <hip/hip_runtime.h>
#include <stdint.h>

#define N_TOK   16384
#define DMODEL  1024
#define NEXP    8
#define DFF     4096
#define CAP     8192
#define MAXB2   264          // 32768/128 + 8 (per-expert 128-row padding)
#define W_LOAD_C 0.01f

typedef __attribute__((ext_vector_type(8))) short short8;
typedef __attribute__((ext_vector_type(4))) float f32x4;

__device__ __forceinline__ uint16_t f2bf(float f) {
    uint32_t u = __float_as_uint(f);
    uint32_t r = u + 0x7fffu + ((u >> 16) & 1u);
    return (uint16_t)(r >> 16);
}
__device__ __forceinline__ float bf2f(uint16_t u) {
    return __uint_as_float((uint32_t)u << 16);
}

__device__ __forceinline__ float gelu_tanh(float v) {
    float u = 0.7978845608028654f * (v + 0.044715f * v * v * v);
    float ex = __expf(2.0f * u);
    float th = 1.0f - 2.0f / (ex + 1.0f);
    return 0.5f * v * (1.0f + th);
}

__device__ __forceinline__ void glds16(const uint16_t* g, uint16_t* l) {
    __builtin_amdgcn_global_load_lds(
        (const __attribute__((address_space(1))) void*)g,
        (__attribute__((address_space(3))) void*)l, 16, 0, 0);
}

// ---------------- gating + routing + load-loss + fused x->bf16 ----------------
// Dot-product code kept bitwise-identical to the passing rounds.
__global__ __launch_bounds__(512) void gating_kernel(
    const float* __restrict__ x, const float* __restrict__ noise,
    const float* __restrict__ gate_w, const float* __restrict__ noise_w,
    int* __restrict__ cnt, float* __restrict__ loadAcc,
    int* __restrict__ rowlist, float* __restrict__ slotw,
    int* __restrict__ tpos0, int* __restrict__ tpos1,
    float* __restrict__ tw0, float* __restrict__ tw1,
    uint16_t* __restrict__ xb)
{
    __shared__ float lp[8][8];
    __shared__ int   se1[8], se2[8];
    __shared__ float sw1[8], sw2[8];

    const int lane = threadIdx.x & 63;
    const int wid  = threadIdx.x >> 6;
    const int t = blockIdx.x * 8 + wid;

    const float* xr = x + (size_t)t * DMODEL;
    uint16_t* xbr = xb + (size_t)t * DMODEL;
    float ag[8] = {0,0,0,0,0,0,0,0};
    float an[8] = {0,0,0,0,0,0,0,0};
    for (int j = 0; j < 16; ++j) {
        int idx = j * 64 + lane;
        float xv = xr[idx];
        xbr[idx] = f2bf(xv);
        const float4* gp  = (const float4*)(gate_w  + idx * 8);
        const float4* np_ = (const float4*)(noise_w + idx * 8);
        float4 g0 = gp[0], g1 = gp[1];
        float4 n0 = np_[0], n1 = np_[1];
        ag[0] += xv * g0.x; ag[1] += xv * g0.y; ag[2] += xv * g0.z; ag[3] += xv * g0.w;
        ag[4] += xv * g1.x; ag[5] += xv * g1.y; ag[6] += xv * g1.z; ag[7] += xv * g1.w;
        an[0] += xv * n0.x; an[1] += xv * n0.y; an[2] += xv * n0.z; an[3] += xv * n0.w;
        an[4] += xv * n1.x; an[5] += xv * n1.y; an[6] += xv * n1.z; an[7] += xv * n1.w;
    }
    #pragma unroll
    for (int m = 32; m >= 1; m >>= 1) {
        #pragma unroll
        for (int e = 0; e < 8; ++e) {
            ag[e] += __shfl_xor(ag[e], m, 64);
            an[e] += __shfl_xor(an[e], m, 64);
        }
    }
    float logit[8], sdv[8];
    #pragma unroll
    for (int e = 0; e < 8; ++e) {
        float a = an[e];
        float sp = (a > 20.0f) ? a : log1pf(expf(a));
        sdv[e] = sp;
        logit[e] = ag[e] + noise[(size_t)t * 8 + e] * sp;
    }
    float v1 = -1e30f, v2 = -1e30f, v3 = -1e30f; int i1 = 0, i2 = 0;
    #pragma unroll
    for (int e = 0; e < 8; ++e) {
        float v = logit[e];
        if (v > v1)      { v3 = v2; v2 = v1; i2 = i1; v1 = v; i1 = e; }
        else if (v > v2) { v3 = v2; v2 = v; i2 = e; }
        else if (v > v3) { v3 = v; }
    }
    if (lane < 8) {
        float kth = (lane == i1 || lane == i2) ? v3 : v2;
        float z = (logit[lane] - kth) / sdv[lane];
        lp[wid][lane] = 0.5f * erfcf(-z * 0.70710678118654752440f);
    }
    if (lane == 0) {
        float e2 = expf(v2 - v1);
        float inv = 1.0f / (1.0f + e2);
        se1[wid] = i1; se2[wid] = i2;
        sw1[wid] = inv; sw2[wid] = e2 * inv;
        tw0[t] = inv; tw1[t] = e2 * inv;
    }
    __syncthreads();
    if (threadIdx.x < 8) {
        int e = threadIdx.x;
        float s = 0.f;
        #pragma unroll
        for (int w = 0; w < 8; ++w) s += lp[w][e];
        atomicAdd(&loadAcc[e], s);
        int m = 0;
        #pragma unroll
        for (int w = 0; w < 8; ++w) m += (se1[w] == e) + (se2[w] == e);
        if (m > 0) {
            int b = atomicAdd(&cnt[e], m);
            #pragma unroll
            for (int w = 0; w < 8; ++w) {
                int tok = blockIdx.x * 8 + w;
                if (se1[w] == e) {
                    if (b < CAP) { rowlist[e * CAP + b] = tok; slotw[e * CAP + b] = sw1[w]; }
                    tpos0[tok] = e * 32768 + b;
                    b++;
                }
                if (se2[w] == e) {
                    if (b < CAP) { rowlist[e * CAP + b] = tok; slotw[e * CAP + b] = sw2[w]; }
                    tpos1[tok] = e * 32768 + b;
                    b++;
                }
            }
        }
    }
}

// ---------------- block map scan: expert/row per 128-row packed block ----------------
__global__ void scan_kernel(const int* __restrict__ cnt,
                            int* __restrict__ be, int* __restrict__ brow,
                            int* __restrict__ ebase)
{
    if (threadIdx.x == 0 && blockIdx.x == 0) {
        int idx = 0;
        for (int e = 0; e < NEXP; ++e) {
            int ce = cnt[e]; if (ce > CAP) ce = CAP;
            int nb = (ce + 127) >> 7;
            ebase[e] = idx * 128;   // packed base row of expert e
            for (int k = 0; k < nb; ++k) { be[idx] = e; brow[idx] = k * 128; idx++; }
        }
        for (; idx < MAXB2; ++idx) { be[idx] = -1; brow[idx] = 0; }
    }
}

// ---------------- per-expert transpose f32 [R][C] -> bf16 [C][R] ----------------
// r16: 64-row x 32-col tiles so bf16 WRITES are full 128 B lines (the old
// 32x32 tile wrote 64 B half-lines -> 2x write amplification on 128 MB).
__global__ __launch_bounds__(256) void transpose_w_kernel(
    const float* __restrict__ src, uint16_t* __restrict__ dst, int R, int Cc)
{
    __shared__ float tile[64][33];
    const float* s = src + (size_t)blockIdx.z * R * Cc;
    uint16_t*    d = dst + (size_t)blockIdx.z * R * Cc;
    const int c0 = blockIdx.x * 32, r0 = blockIdx.y * 64;
    const int tx = threadIdx.x & 31, ty = threadIdx.x >> 5;     // read: 32x8
    #pragma unroll
    for (int rr = ty; rr < 64; rr += 8)
        tile[rr][tx] = s[(size_t)(r0 + rr) * Cc + c0 + tx];
    __syncthreads();
    const int tx64 = threadIdx.x & 63, tyw = threadIdx.x >> 6;  // write: 64x4
    #pragma unroll
    for (int cc = tyw; cc < 32; cc += 4)
        d[(size_t)(c0 + cc) * R + r0 + tx64] = f2bf(tile[tx64][cc]);
}

// ---------------- GEMM: 128x128 tile, BK=32, 4 waves, 3 blocks/CU ----------------
// r16 = r15 with the GEMM1 supertile enlarged 4x8 -> 8x8: WS = 8 A-panels +
// 8 B-panels = 4 MB = L2 exactly; ~96 concurrent blocks/XCD now span ~1.5
// supertiles (6 MB) instead of 3 (9 MB) -> better L2 fit (FETCH was still
// 2.8x compulsory at 4x8).
template<int KTOT, int GATHER, int GELU, int ATOMIC, int SUPER>
__global__ __launch_bounds__(256, 3) void gemm_kernel(
    const uint16_t* __restrict__ Abase,
    const uint16_t* __restrict__ Bfull,
    const int*      __restrict__ rowlist,
    const float*    __restrict__ slotw,
    const int*      __restrict__ cnt,
    const int*      __restrict__ be,
    const int*      __restrict__ brow,
    const float*    __restrict__ biasFull,
    uint16_t*       __restrict__ OutBf,
    float*          __restrict__ OutF,
    int ncols, int bo)
{
    // 48 KiB: 3 ring slots x (A 8KB: subtiles 0..7 | B 8KB @ +8192).
    // Subtile = 16 rows x 32 K bf16 = 1024 B. Epilogue reuses ring as
    // 128x136 u16 arena. lsm FIRST so LDS base = 0 (imm folding).
    __shared__ uint16_t lsm[24576];
    __shared__ int   lT[128];
    __shared__ float lW[128];

    // bijective XCD swizzle (m204) + optional 8x8 supertile decode
    const int nwg  = gridDim.x * gridDim.y;
    const int flat = blockIdx.y * gridDim.x + blockIdx.x;
    const int xcd = flat & 7, sid = flat >> 3;
    const int q = nwg >> 3, r8_ = nwg & 7;
    const int f2 = (xcd < r8_ ? xcd * (q + 1) : r8_ * (q + 1) + (xcd - r8_) * q) + sid;
    int nx, rbi;
    if (SUPER && ((gridDim.y & 7) == 0) && ((gridDim.x & 7) == 0) &&
        (((gridDim.x >> 3) & ((gridDim.x >> 3) - 1)) == 0)) {
        const int stW = gridDim.x >> 3;      // supertiles per row band (pow2)
        const int st  = f2 >> 6, wi = f2 & 63;
        const int stx = st & (stW - 1);
        const int sty = st / stW;
        nx  = (stx << 3) | (wi & 7);
        rbi = (sty << 3) | (wi >> 3);
    } else {
        nx  = f2 % gridDim.x;
        rbi = f2 / gridDim.x;
    }

    const int rb = rbi + bo;
    if (rb >= MAXB2) return;
    const int e = be[rb];
    if (e < 0) return;
    const int row0 = brow[rb];
    int ce = cnt[e]; if (ce > CAP) ce = CAP;
    const int n0 = nx * 128;

    const int t    = threadIdx.x;
    const int lane = t & 63, wid = t >> 6;          // 4 waves
    const int fr = lane & 15, ks = lane >> 4;
    const int wr = wid >> 1, wc = wid & 1;          // 2(M) x 2(N) wave grid

    if (ATOMIC) {
        if (t < 128) {
            int rr = row0 + t;
            int rc = (rr < ce) ? rr : (ce - 1);
            lT[t] = rowlist[e * CAP + rc];
            lW[t] = (rr < ce) ? slotw[e * CAP + rr] : 0.0f;
        }
        __syncthreads();
    }

    // ---- staging: instr j (0,1) fills subtile wid+4j; lane l covers bytes
    // [l*16, l*16+16). st_16x32 inverse swizzle on the SOURCE granule.
    const uint16_t* Bp = Bfull + (size_t)e * ncols * KTOT;
    const int rsub = lane >> 2;
    const int kof  = ((lane & 3) ^ (((lane >> 5) & 1) << 1)) * 8;
    const int rowT0 = wid * 16 + rsub;          // subtiles 0..3
    const int rowT1 = 64 + wid * 16 + rsub;     // subtiles 4..7
    size_t gr0, gr1;
    if (GATHER) {
        int r0c = row0 + rowT0; r0c = (r0c < ce) ? r0c : (ce - 1);
        int r1c = row0 + rowT1; r1c = (r1c < ce) ? r1c : (ce - 1);
        gr0 = (size_t)rowlist[e * CAP + r0c];
        gr1 = (size_t)rowlist[e * CAP + r1c];
    } else {
        gr0 = (size_t)rbi * 128 + rowT0;
        gr1 = (size_t)rbi * 128 + rowT1;
    }
    const uint16_t* pA0 = Abase + gr0 * KTOT + kof;
    const uint16_t* pA1 = Abase + gr1 * KTOT + kof;
    const uint16_t* pB0 = Bp + (size_t)(n0 + rowT0) * KTOT + kof;
    const uint16_t* pB1 = Bp + (size_t)(n0 + rowT1) * KTOT + kof;
    const int dA0 = wid * 1024 + lane * 16;     // LDS byte offsets (linear dest)
    const int dA1 = (4 + wid) * 1024 + lane * 16;
    const int dB0 = 8192 + dA0;
    const int dB1 = 8192 + dA1;

    // ---- ds_read byte offsets within slot 0 (swizzled; conflicts = 0) ----
    const int sw = (ks * 16) ^ ((fr >> 3) << 5);
    int aOff[4], bOff[4];
    #pragma unroll
    for (int m = 0; m < 4; ++m) aOff[m] = (wr * 4 + m) * 1024 + fr * 64 + sw;
    #pragma unroll
    for (int n = 0; n < 4; ++n) bOff[n] = 8192 + (wc * 4 + n) * 1024 + fr * 64 + sw;

    f32x4 acc[4][4];
    #pragma unroll
    for (int a = 0; a < 4; ++a)
        #pragma unroll
        for (int b = 0; b < 4; ++b) acc[a][b] = (f32x4){0.f, 0.f, 0.f, 0.f};

    constexpr int NKT = KTOT / 32;
    char* lsb = (char*)lsm;

    // prologue: stage K-tiles 0,1 into slots 0,1; wait tile 0 (4 in flight)
    #pragma unroll
    for (int p = 0; p < 2; ++p) {
        char* db = lsb + p * 16384;
        glds16(pA0 + p * 32, (uint16_t*)(db + dA0));
        glds16(pA1 + p * 32, (uint16_t*)(db + dA1));
        glds16(pB0 + p * 32, (uint16_t*)(db + dB0));
        glds16(pB1 + p * 32, (uint16_t*)(db + dB1));
    }
    asm volatile("s_waitcnt vmcnt(4)" ::: "memory");
    __builtin_amdgcn_s_barrier();
    asm volatile("" ::: "memory");

    // K-loop unrolled by 3: RS_ = read slot (compile-time), SS_ = stage slot,
    // SOFF_ = stage element offset from the triple-base pointers.
#define K_STEP(KT_, RS_, SS_, SOFF_)                                         \
  {                                                                          \
    if ((KT_) + 2 < NKT) {                                                   \
      glds16(pA0 + (SOFF_), (uint16_t*)(lsb + (SS_) * 16384 + dA0));         \
      glds16(pA1 + (SOFF_), (uint16_t*)(lsb + (SS_) * 16384 + dA1));         \
      glds16(pB0 + (SOFF_), (uint16_t*)(lsb + (SS_) * 16384 + dB0));         \
      glds16(pB1 + (SOFF_), (uint16_t*)(lsb + (SS_) * 16384 + dB1));         \
    }                                                                        \
    short8 af[4], bf[4];                                                     \
    _Pragma("unroll")                                                        \
    for (int m = 0; m < 4; ++m)                                              \
      af[m] = *(const short8*)(lsb + (RS_) * 16384 + aOff[m]);               \
    _Pragma("unroll")                                                        \
    for (int n = 0; n < 4; ++n)                                              \
      bf[n] = *(const short8*)(lsb + (RS_) * 16384 + bOff[n]);               \
    __builtin_amdgcn_s_setprio(1);                                           \
    _Pragma("unroll")                                                        \
    for (int m = 0; m < 4; ++m)                                              \
      _Pragma("unroll")                                                      \
      for (int n = 0; n < 4; ++n)                                            \
        acc[m][n] = __builtin_amdgcn_mfma_f32_16x16x32_bf16(                 \
            af[m], bf[n], acc[m][n], 0, 0, 0);                               \
    __builtin_amdgcn_s_setprio(0);                                           \
    {                                                                        \
      const int rem_ = NKT - 1 - (KT_);                                      \
      if (rem_ >= 2)      asm volatile("s_waitcnt vmcnt(4)" ::: "memory");   \
      else if (rem_ == 1) asm volatile("s_waitcnt vmcnt(0)" ::: "memory");   \
    }                                                                        \
    asm volatile("" ::: "memory");                                           \
    __builtin_amdgcn_s_barrier();                                            \
    asm volatile("" ::: "memory");                                           \
  }

    for (int ktb = 0; ktb < NKT; ktb += 3) {
        K_STEP(ktb,     0, 2, 64);
        if (ktb + 1 < NKT) K_STEP(ktb + 1, 1, 0, 96);
        if (ktb + 2 < NKT) K_STEP(ktb + 2, 2, 1, 128);
        pA0 += 96; pA1 += 96; pB0 += 96; pB1 += 96;
    }
#undef K_STEP

    // ---- epilogue: D mapping col = lane&15, row = (lane>>4)*4 + j [m89/m91] ----
    const float* bias = biasFull + (size_t)e * ncols;
    if (ATOMIC) {
        #pragma unroll
        for (int mi = 0; mi < 4; ++mi) {
            const int rbase = wr * 64 + mi * 16 + ks * 4;
            #pragma unroll
            for (int ni = 0; ni < 4; ++ni) {
                const int c = n0 + wc * 64 + ni * 16 + fr;
                const float bv = bias[c];
                #pragma unroll
                for (int j = 0; j < 4; ++j) {
                    const int rl = rbase + j;
                    if (row0 + rl < ce) {
                        float v = acc[mi][ni][j] + bv;
                        atomicAdd(&OutF[(size_t)lT[rl] * DMODEL + c], lW[rl] * v);
                    }
                }
            }
        }
    } else {
        // staged, coalesced stores via the LDS arena (128 x 128 u16, stride 136)
        __syncthreads();
        #pragma unroll
        for (int mi = 0; mi < 4; ++mi) {
            #pragma unroll
            for (int ni = 0; ni < 4; ++ni) {
                const int cl = wc * 64 + ni * 16 + fr;
                const float bv = bias[n0 + cl];
                #pragma unroll
                for (int j = 0; j < 4; ++j) {
                    float v = acc[mi][ni][j] + bv;
                    if (GELU) v = gelu_tanh(v);
                    const int rl = wr * 64 + mi * 16 + ks * 4 + j;
                    lsm[rl * 136 + cl] = f2bf(v);
                }
            }
        }
        __syncthreads();
        const int r2 = t >> 1, hcol = (t & 1) * 64;
        uint16_t* gp = OutBf + ((size_t)rbi * 128 + r2) * ncols + n0 + hcol;
        #pragma unroll
        for (int j2 = 0; j2 < 8; ++j2) {
            short8 v = *(const short8*)&lsm[r2 * 136 + hcol + j2 * 8];
            *(short8*)(gp + j2 * 8) = v;
        }
    }
}

// ---------------- combine: out[t] = w0*y2[p0] + w1*y2[p1] (gather, no atomics) ----
__global__ __launch_bounds__(256) void combine_kernel(
    const uint16_t* __restrict__ y2,
    const int* __restrict__ tpos0, const int* __restrict__ tpos1,
    const float* __restrict__ tw0, const float* __restrict__ tw1,
    const int* __restrict__ ebase, float* __restrict__ out)
{
    const int wid = threadIdx.x >> 6, lane = threadIdx.x & 63;
    const int t = blockIdx.x * 4 + wid;
    const int p0 = tpos0[t], p1 = tpos1[t];
    const int e0 = p0 >> 15, s0 = p0 & 32767;
    const int e1 = p1 >> 15, s1 = p1 & 32767;
    const bool v0 = s0 < CAP, v1 = s1 < CAP;
    const float w0 = v0 ? tw0[t] : 0.0f;
    const float w1 = v1 ? tw1[t] : 0.0f;
    const uint16_t* r0p = y2 + ((size_t)ebase[e0] + (v0 ? s0 : 0)) * DMODEL;
    const uint16_t* r1p = y2 + ((size_t)ebase[e1] + (v1 ? s1 : 0)) * DMODEL;
    float* op = out + (size_t)t * DMODEL;
    #pragma unroll
    for (int half = 0; half < 2; ++half) {
        const int off = half * 512 + lane * 8;
        short8 a = *(const short8*)(r0p + off);
        short8 b = *(const short8*)(r1p + off);
        float4 o0, o1;
        o0.x = w0 * bf2f((uint16_t)a[0]) + w1 * bf2f((uint16_t)b[0]);
        o0.y = w0 * bf2f((uint16_t)a[1]) + w1 * bf2f((uint16_t)b[1]);
        o0.z = w0 * bf2f((uint16_t)a[2]) + w1 * bf2f((uint16_t)b[2]);
        o0.w = w0 * bf2f((uint16_t)a[3]) + w1 * bf2f((uint16_t)b[3]);
        o1.x = w0 * bf2f((uint16_t)a[4]) + w1 * bf2f((uint16_t)b[4]);
        o1.y = w0 * bf2f((uint16_t)a[5]) + w1 * bf2f((uint16_t)b[5]);
        o1.z = w0 * bf2f((uint16_t)a[6]) + w1 * bf2f((uint16_t)b[6]);
        o1.w = w0 * bf2f((uint16_t)a[7]) + w1 * bf2f((uint16_t)b[7]);
        *(float4*)(op + off)     = o0;
        *(float4*)(op + off + 4) = o1;
    }
}

// ---------------- load-loss finalize ----------------
__global__ void finalize_kernel(const float* __restrict__ loadAcc, float* __restrict__ out) {
    if (threadIdx.x == 0) {
        float m = 0.f;
        #pragma unroll
        for (int e = 0; e < 8; ++e) m += loadAcc[e];
        m *= 0.125f;
        float v = 0.f;
        #pragma unroll
        for (int e = 0; e < 8; ++e) { float d0 = loadAcc[e] - m; v += d0 * d0; }
        v *= (1.0f / 7.0f);   // ddof=1
        out[(size_t)N_TOK * DMODEL] = W_LOAD_C * v / (m * m);
    }
}

extern "C" void kernel_launch(void* const* d_in, const int* in_sizes, int n_in,
                              void* d_out, int out_size, void* d_ws, size_t ws_size,
                              hipStream_t stream) {
    const float* x       = (const float*)d_in[0];
    const float* noise   = (const float*)d_in[1];
    const float* gate_w  = (const float*)d_in[2];
    const float* noise_w = (const float*)d_in[3];
    const float* w1      = (const float*)d_in[4];
    const float* b1      = (const float*)d_in[5];
    const float* w2      = (const float*)d_in[6];
    const float* b2      = (const float*)d_in[7];
    float* out = (float*)d_out;
    char* ws = (char*)d_ws;

    int*      cnt     = (int*)(ws + 0);
    float*    loadAcc = (float*)(ws + 256);
    int*      ebase   = (int*)(ws + 512);
    int*      be      = (int*)(ws + 1024);        // 264 ints
    int*      brow    = (int*)(ws + 3072);        // 264 ints
    int*      rowlist = (int*)(ws + 8192);        // 256 KiB
    int*      tpos0   = (int*)(ws + 270336);      // 64 KiB each
    int*      tpos1   = (int*)(ws + 335872);
    float*    tw0     = (float*)(ws + 401408);
    float*    tw1     = (float*)(ws + 466944);
    float*    slotw   = (float*)(ws + 532480);    // 256 KiB (fallback only)
    uint16_t* xb      = (uint16_t*)(ws + 794624); // 32 MiB
    uint16_t* w1t     = (uint16_t*)(ws + 34349056);  // 64 MiB
    uint16_t* w2t     = (uint16_t*)(ws + 101457920); // 64 MiB
    uint16_t* h       = (uint16_t*)(ws + 168566784); // 264*128 x 4096 bf16
    const size_t HOFF = 168566784ull;
    const size_t HSZ  = (size_t)MAXB2 * 128 * DFF * 2;     // 276,824,064
    uint16_t* y2      = (uint16_t*)(ws + HOFF + HSZ);      // packed y+b2 bf16
    const size_t Y2SZ = (size_t)MAXB2 * 128 * DMODEL * 2;  // 69,206,016
    const bool gatherPath = ws_size >= HOFF + HSZ + Y2SZ;

    hipMemsetAsync(ws, 0, 4096, stream);

    gating_kernel<<<2048, 512, 0, stream>>>(x, noise, gate_w, noise_w,
                                            cnt, loadAcc, rowlist, slotw,
                                            tpos0, tpos1, tw0, tw1, xb);
    scan_kernel<<<1, 64, 0, stream>>>(cnt, be, brow, ebase);
    transpose_w_kernel<<<dim3(128, 16, 8), 256, 0, stream>>>(w1, w1t, 1024, 4096);
    transpose_w_kernel<<<dim3(32, 64, 8), 256, 0, stream>>>(w2, w2t, 4096, 1024);
    finalize_kernel<<<1, 64, 0, stream>>>(loadAcc, out);

    if (gatherPath) {
        gemm_kernel<1024, 1, 1, 0, 1><<<dim3(32, MAXB2), 256, 0, stream>>>(
            xb, w1t, rowlist, slotw, cnt, be, brow, b1, h, nullptr, DFF, 0);
        gemm_kernel<4096, 0, 0, 0, 0><<<dim3(8, MAXB2), 256, 0, stream>>>(
            h, w2t, rowlist, slotw, cnt, be, brow, b2, y2, nullptr, DMODEL, 0);
        combine_kernel<<<4096, 256, 0, stream>>>(y2, tpos0, tpos1, tw0, tw1,
                                                 ebase, out);
    } else {
        // fallback: atomic combine (chunked if h doesn't fit)
        hipMemsetAsync(d_out, 0, (size_t)out_size * sizeof(float), stream);
        size_t avail = (ws_size > HOFF) ? ws_size - HOFF : 0;
        int nch = 8, bpc = (MAXB2 + 7) / 8;
        for (int c = 1; c <= 8; c <<= 1) {
            int b = (MAXB2 + c - 1) / c;
            if ((size_t)b * 128 * DFF * 2 <= avail) { nch = c; bpc = b; break; }
        }
        for (int c = 0; c < nch; ++c) {
            int bo = c * bpc;
            if (bo >= MAXB2) break;
            gemm_kernel<1024, 1, 1, 0, 0><<<dim3(32, bpc), 256, 0, stream>>>(
                xb, w1t, rowlist, slotw, cnt, be, brow, b1, h, nullptr, DFF, bo);
            gemm_kernel<4096, 0, 0, 1, 0><<<dim3(8, bpc), 256, 0, stream>>>(
                h, w2t, rowlist, slotw, cnt, be, brow, b2, nullptr, out, DMODEL, bo);
        }
    }
}

// Round 17
// 941.339 us; speedup vs baseline: 1.4100x; 1.0077x over previous
//
#include <hip/hip_runtime.h>
#include <stdint.h>

#define N_TOK   16384
#define DMODEL  1024
#define NEXP    8
#define DFF     4096
#define CAP     8192
#define MAXB2   264          // 32768/128 + 8 (per-expert 128-row padding)
#define W_LOAD_C 0.01f

typedef __attribute__((ext_vector_type(8))) short short8;
typedef __attribute__((ext_vector_type(4))) float f32x4;

__device__ __forceinline__ uint16_t f2bf(float f) {
    uint32_t u = __float_as_uint(f);
    uint32_t r = u + 0x7fffu + ((u >> 16) & 1u);
    return (uint16_t)(r >> 16);
}
__device__ __forceinline__ float bf2f(uint16_t u) {
    return __uint_as_float((uint32_t)u << 16);
}

__device__ __forceinline__ float gelu_tanh(float v) {
    float u = 0.7978845608028654f * (v + 0.044715f * v * v * v);
    float ex = __expf(2.0f * u);
    float th = 1.0f - 2.0f / (ex + 1.0f);
    return 0.5f * v * (1.0f + th);
}

__device__ __forceinline__ void glds16(const uint16_t* g, uint16_t* l) {
    __builtin_amdgcn_global_load_lds(
        (const __attribute__((address_space(1))) void*)g,
        (__attribute__((address_space(3))) void*)l, 16, 0, 0);
}

// ---------------- gating + routing + load-loss + fused x->bf16 ----------------
// Dot-product code kept bitwise-identical to the passing rounds.
__global__ __launch_bounds__(512) void gating_kernel(
    const float* __restrict__ x, const float* __restrict__ noise,
    const float* __restrict__ gate_w, const float* __restrict__ noise_w,
    int* __restrict__ cnt, float* __restrict__ loadAcc,
    int* __restrict__ rowlist, float* __restrict__ slotw,
    int* __restrict__ tpos0, int* __restrict__ tpos1,
    float* __restrict__ tw0, float* __restrict__ tw1,
    uint16_t* __restrict__ xb)
{
    __shared__ float lp[8][8];
    __shared__ int   se1[8], se2[8];
    __shared__ float sw1[8], sw2[8];

    const int lane = threadIdx.x & 63;
    const int wid  = threadIdx.x >> 6;
    const int t = blockIdx.x * 8 + wid;

    const float* xr = x + (size_t)t * DMODEL;
    uint16_t* xbr = xb + (size_t)t * DMODEL;
    float ag[8] = {0,0,0,0,0,0,0,0};
    float an[8] = {0,0,0,0,0,0,0,0};
    for (int j = 0; j < 16; ++j) {
        int idx = j * 64 + lane;
        float xv = xr[idx];
        xbr[idx] = f2bf(xv);
        const float4* gp  = (const float4*)(gate_w  + idx * 8);
        const float4* np_ = (const float4*)(noise_w + idx * 8);
        float4 g0 = gp[0], g1 = gp[1];
        float4 n0 = np_[0], n1 = np_[1];
        ag[0] += xv * g0.x; ag[1] += xv * g0.y; ag[2] += xv * g0.z; ag[3] += xv * g0.w;
        ag[4] += xv * g1.x; ag[5] += xv * g1.y; ag[6] += xv * g1.z; ag[7] += xv * g1.w;
        an[0] += xv * n0.x; an[1] += xv * n0.y; an[2] += xv * n0.z; an[3] += xv * n0.w;
        an[4] += xv * n1.x; an[5] += xv * n1.y; an[6] += xv * n1.z; an[7] += xv * n1.w;
    }
    #pragma unroll
    for (int m = 32; m >= 1; m >>= 1) {
        #pragma unroll
        for (int e = 0; e < 8; ++e) {
            ag[e] += __shfl_xor(ag[e], m, 64);
            an[e] += __shfl_xor(an[e], m, 64);
        }
    }
    float logit[8], sdv[8];
    #pragma unroll
    for (int e = 0; e < 8; ++e) {
        float a = an[e];
        float sp = (a > 20.0f) ? a : log1pf(expf(a));
        sdv[e] = sp;
        logit[e] = ag[e] + noise[(size_t)t * 8 + e] * sp;
    }
    float v1 = -1e30f, v2 = -1e30f, v3 = -1e30f; int i1 = 0, i2 = 0;
    #pragma unroll
    for (int e = 0; e < 8; ++e) {
        float v = logit[e];
        if (v > v1)      { v3 = v2; v2 = v1; i2 = i1; v1 = v; i1 = e; }
        else if (v > v2) { v3 = v2; v2 = v; i2 = e; }
        else if (v > v3) { v3 = v; }
    }
    if (lane < 8) {
        float kth = (lane == i1 || lane == i2) ? v3 : v2;
        float z = (logit[lane] - kth) / sdv[lane];
        lp[wid][lane] = 0.5f * erfcf(-z * 0.70710678118654752440f);
    }
    if (lane == 0) {
        float e2 = expf(v2 - v1);
        float inv = 1.0f / (1.0f + e2);
        se1[wid] = i1; se2[wid] = i2;
        sw1[wid] = inv; sw2[wid] = e2 * inv;
        tw0[t] = inv; tw1[t] = e2 * inv;
    }
    __syncthreads();
    if (threadIdx.x < 8) {
        int e = threadIdx.x;
        float s = 0.f;
        #pragma unroll
        for (int w = 0; w < 8; ++w) s += lp[w][e];
        atomicAdd(&loadAcc[e], s);
        int m = 0;
        #pragma unroll
        for (int w = 0; w < 8; ++w) m += (se1[w] == e) + (se2[w] == e);
        if (m > 0) {
            int b = atomicAdd(&cnt[e], m);
            #pragma unroll
            for (int w = 0; w < 8; ++w) {
                int tok = blockIdx.x * 8 + w;
                if (se1[w] == e) {
                    if (b < CAP) { rowlist[e * CAP + b] = tok; slotw[e * CAP + b] = sw1[w]; }
                    tpos0[tok] = e * 32768 + b;
                    b++;
                }
                if (se2[w] == e) {
                    if (b < CAP) { rowlist[e * CAP + b] = tok; slotw[e * CAP + b] = sw2[w]; }
                    tpos1[tok] = e * 32768 + b;
                    b++;
                }
            }
        }
    }
}

// ---------------- block map scan: PARALLEL (was serial 1-thread) ----------------
__global__ void scan_kernel(const int* __restrict__ cnt,
                            int* __restrict__ be, int* __restrict__ brow,
                            int* __restrict__ ebase)
{
    __shared__ int base[9];
    if (threadIdx.x < 8) {
        int acc = 0;
        for (int e = 0; e < (int)threadIdx.x; ++e) {
            int ce = cnt[e]; if (ce > CAP) ce = CAP;
            acc += (ce + 127) >> 7;
        }
        base[threadIdx.x] = acc;
        ebase[threadIdx.x] = acc * 128;
        if (threadIdx.x == 7) {
            int ce = cnt[7]; if (ce > CAP) ce = CAP;
            base[8] = acc + ((ce + 127) >> 7);
        }
    }
    __syncthreads();
    for (int b = threadIdx.x; b < MAXB2; b += blockDim.x) {
        int e = -1, k = 0;
        #pragma unroll
        for (int ee = 0; ee < 8; ++ee)
            if (b >= base[ee] && b < base[ee + 1]) { e = ee; k = b - base[ee]; }
        be[b] = e;
        brow[b] = k * 128;
    }
}

// ---------------- per-expert transpose f32 [R][C] -> bf16 [C][R] ----------------
// 64-row x 32-col tiles: bf16 writes are full 128 B lines (r16).
__global__ __launch_bounds__(256) void transpose_w_kernel(
    const float* __restrict__ src, uint16_t* __restrict__ dst, int R, int Cc)
{
    __shared__ float tile[64][33];
    const float* s = src + (size_t)blockIdx.z * R * Cc;
    uint16_t*    d = dst + (size_t)blockIdx.z * R * Cc;
    const int c0 = blockIdx.x * 32, r0 = blockIdx.y * 64;
    const int tx = threadIdx.x & 31, ty = threadIdx.x >> 5;     // read: 32x8
    #pragma unroll
    for (int rr = ty; rr < 64; rr += 8)
        tile[rr][tx] = s[(size_t)(r0 + rr) * Cc + c0 + tx];
    __syncthreads();
    const int tx64 = threadIdx.x & 63, tyw = threadIdx.x >> 6;  // write: 64x4
    #pragma unroll
    for (int cc = tyw; cc < 32; cc += 4)
        d[(size_t)(c0 + cc) * R + r0 + tx64] = f2bf(tile[tx64][cc]);
}

// ---------------- GEMM: 128x128 tile, BK=32, 4 waves, 3 blocks/CU ----------------
// r17 = r16 + SUPER==2: 2x2 supertile for GEMM2 (WS = 2 A-panels + 2 B-panels
// = 4 MB = L2; GEMM2's 1 MB K=4096 panels never fit the 4x8/8x8 shapes).
// SUPER==1: 8x8 supertile (GEMM1). K-loop unchanged from r14/r16.
template<int KTOT, int GATHER, int GELU, int ATOMIC, int SUPER>
__global__ __launch_bounds__(256, 3) void gemm_kernel(
    const uint16_t* __restrict__ Abase,
    const uint16_t* __restrict__ Bfull,
    const int*      __restrict__ rowlist,
    const float*    __restrict__ slotw,
    const int*      __restrict__ cnt,
    const int*      __restrict__ be,
    const int*      __restrict__ brow,
    const float*    __restrict__ biasFull,
    uint16_t*       __restrict__ OutBf,
    float*          __restrict__ OutF,
    int ncols, int bo)
{
    // 48 KiB: 3 ring slots x (A 8KB: subtiles 0..7 | B 8KB @ +8192).
    // Subtile = 16 rows x 32 K bf16 = 1024 B. Epilogue reuses ring as
    // 128x136 u16 arena. lsm FIRST so LDS base = 0 (imm folding).
    __shared__ uint16_t lsm[24576];
    __shared__ int   lT[128];
    __shared__ float lW[128];

    // bijective XCD swizzle (m204) + optional supertile decode
    const int nwg  = gridDim.x * gridDim.y;
    const int flat = blockIdx.y * gridDim.x + blockIdx.x;
    const int xcd = flat & 7, sid = flat >> 3;
    const int q = nwg >> 3, r8_ = nwg & 7;
    const int f2 = (xcd < r8_ ? xcd * (q + 1) : r8_ * (q + 1) + (xcd - r8_) * q) + sid;
    int nx, rbi;
    if (SUPER == 1 && ((gridDim.y & 7) == 0) && ((gridDim.x & 7) == 0) &&
        (((gridDim.x >> 3) & ((gridDim.x >> 3) - 1)) == 0)) {
        const int stW = gridDim.x >> 3;      // supertiles per row band (pow2)
        const int st  = f2 >> 6, wi = f2 & 63;
        const int stx = st & (stW - 1);
        const int sty = st / stW;
        nx  = (stx << 3) | (wi & 7);
        rbi = (sty << 3) | (wi >> 3);
    } else if (SUPER == 2 && ((gridDim.y & 1) == 0) && ((gridDim.x & 1) == 0) &&
        (((gridDim.x >> 1) & ((gridDim.x >> 1) - 1)) == 0)) {
        const int stW = gridDim.x >> 1;      // 2x2 supertile (pow2 stW)
        const int st  = f2 >> 2, wi = f2 & 3;
        const int stx = st & (stW - 1);
        const int sty = st / stW;
        nx  = (stx << 1) | (wi & 1);
        rbi = (sty << 1) | (wi >> 1);
    } else {
        nx  = f2 % gridDim.x;
        rbi = f2 / gridDim.x;
    }

    const int rb = rbi + bo;
    if (rb >= MAXB2) return;
    const int e = be[rb];
    if (e < 0) return;
    const int row0 = brow[rb];
    int ce = cnt[e]; if (ce > CAP) ce = CAP;
    const int n0 = nx * 128;

    const int t    = threadIdx.x;
    const int lane = t & 63, wid = t >> 6;          // 4 waves
    const int fr = lane & 15, ks = lane >> 4;
    const int wr = wid >> 1, wc = wid & 1;          // 2(M) x 2(N) wave grid

    if (ATOMIC) {
        if (t < 128) {
            int rr = row0 + t;
            int rc = (rr < ce) ? rr : (ce - 1);
            lT[t] = rowlist[e * CAP + rc];
            lW[t] = (rr < ce) ? slotw[e * CAP + rr] : 0.0f;
        }
        __syncthreads();
    }

    // ---- staging: instr j (0,1) fills subtile wid+4j; lane l covers bytes
    // [l*16, l*16+16). st_16x32 inverse swizzle on the SOURCE granule.
    const uint16_t* Bp = Bfull + (size_t)e * ncols * KTOT;
    const int rsub = lane >> 2;
    const int kof  = ((lane & 3) ^ (((lane >> 5) & 1) << 1)) * 8;
    const int rowT0 = wid * 16 + rsub;          // subtiles 0..3
    const int rowT1 = 64 + wid * 16 + rsub;     // subtiles 4..7
    size_t gr0, gr1;
    if (GATHER) {
        int r0c = row0 + rowT0; r0c = (r0c < ce) ? r0c : (ce - 1);
        int r1c = row0 + rowT1; r1c = (r1c < ce) ? r1c : (ce - 1);
        gr0 = (size_t)rowlist[e * CAP + r0c];
        gr1 = (size_t)rowlist[e * CAP + r1c];
    } else {
        gr0 = (size_t)rbi * 128 + rowT0;
        gr1 = (size_t)rbi * 128 + rowT1;
    }
    const uint16_t* pA0 = Abase + gr0 * KTOT + kof;
    const uint16_t* pA1 = Abase + gr1 * KTOT + kof;
    const uint16_t* pB0 = Bp + (size_t)(n0 + rowT0) * KTOT + kof;
    const uint16_t* pB1 = Bp + (size_t)(n0 + rowT1) * KTOT + kof;
    const int dA0 = wid * 1024 + lane * 16;     // LDS byte offsets (linear dest)
    const int dA1 = (4 + wid) * 1024 + lane * 16;
    const int dB0 = 8192 + dA0;
    const int dB1 = 8192 + dA1;

    // ---- ds_read byte offsets within slot 0 (swizzled; conflicts = 0) ----
    const int sw = (ks * 16) ^ ((fr >> 3) << 5);
    int aOff[4], bOff[4];
    #pragma unroll
    for (int m = 0; m < 4; ++m) aOff[m] = (wr * 4 + m) * 1024 + fr * 64 + sw;
    #pragma unroll
    for (int n = 0; n < 4; ++n) bOff[n] = 8192 + (wc * 4 + n) * 1024 + fr * 64 + sw;

    f32x4 acc[4][4];
    #pragma unroll
    for (int a = 0; a < 4; ++a)
        #pragma unroll
        for (int b = 0; b < 4; ++b) acc[a][b] = (f32x4){0.f, 0.f, 0.f, 0.f};

    constexpr int NKT = KTOT / 32;
    char* lsb = (char*)lsm;

    // prologue: stage K-tiles 0,1 into slots 0,1; wait tile 0 (4 in flight)
    #pragma unroll
    for (int p = 0; p < 2; ++p) {
        char* db = lsb + p * 16384;
        glds16(pA0 + p * 32, (uint16_t*)(db + dA0));
        glds16(pA1 + p * 32, (uint16_t*)(db + dA1));
        glds16(pB0 + p * 32, (uint16_t*)(db + dB0));
        glds16(pB1 + p * 32, (uint16_t*)(db + dB1));
    }
    asm volatile("s_waitcnt vmcnt(4)" ::: "memory");
    __builtin_amdgcn_s_barrier();
    asm volatile("" ::: "memory");

    // K-loop unrolled by 3: RS_ = read slot (compile-time), SS_ = stage slot,
    // SOFF_ = stage element offset from the triple-base pointers.
#define K_STEP(KT_, RS_, SS_, SOFF_)                                         \
  {                                                                          \
    if ((KT_) + 2 < NKT) {                                                   \
      glds16(pA0 + (SOFF_), (uint16_t*)(lsb + (SS_) * 16384 + dA0));         \
      glds16(pA1 + (SOFF_), (uint16_t*)(lsb + (SS_) * 16384 + dA1));         \
      glds16(pB0 + (SOFF_), (uint16_t*)(lsb + (SS_) * 16384 + dB0));         \
      glds16(pB1 + (SOFF_), (uint16_t*)(lsb + (SS_) * 16384 + dB1));         \
    }                                                                        \
    short8 af[4], bf[4];                                                     \
    _Pragma("unroll")                                                        \
    for (int m = 0; m < 4; ++m)                                              \
      af[m] = *(const short8*)(lsb + (RS_) * 16384 + aOff[m]);               \
    _Pragma("unroll")                                                        \
    for (int n = 0; n < 4; ++n)                                              \
      bf[n] = *(const short8*)(lsb + (RS_) * 16384 + bOff[n]);               \
    __builtin_amdgcn_s_setprio(1);                                           \
    _Pragma("unroll")                                                        \
    for (int m = 0; m < 4; ++m)                                              \
      _Pragma("unroll")                                                      \
      for (int n = 0; n < 4; ++n)                                            \
        acc[m][n] = __builtin_amdgcn_mfma_f32_16x16x32_bf16(                 \
            af[m], bf[n], acc[m][n], 0, 0, 0);                               \
    __builtin_amdgcn_s_setprio(0);                                           \
    {                                                                        \
      const int rem_ = NKT - 1 - (KT_);                                      \
      if (rem_ >= 2)      asm volatile("s_waitcnt vmcnt(4)" ::: "memory");   \
      else if (rem_ == 1) asm volatile("s_waitcnt vmcnt(0)" ::: "memory");   \
    }                                                                        \
    asm volatile("" ::: "memory");                                           \
    __builtin_amdgcn_s_barrier();                                            \
    asm volatile("" ::: "memory");                                           \
  }

    for (int ktb = 0; ktb < NKT; ktb += 3) {
        K_STEP(ktb,     0, 2, 64);
        if (ktb + 1 < NKT) K_STEP(ktb + 1, 1, 0, 96);
        if (ktb + 2 < NKT) K_STEP(ktb + 2, 2, 1, 128);
        pA0 += 96; pA1 += 96; pB0 += 96; pB1 += 96;
    }
#undef K_STEP

    // ---- epilogue: D mapping col = lane&15, row = (lane>>4)*4 + j [m89/m91] ----
    const float* bias = biasFull + (size_t)e * ncols;
    if (ATOMIC) {
        #pragma unroll
        for (int mi = 0; mi < 4; ++mi) {
            const int rbase = wr * 64 + mi * 16 + ks * 4;
            #pragma unroll
            for (int ni = 0; ni < 4; ++ni) {
                const int c = n0 + wc * 64 + ni * 16 + fr;
                const float bv = bias[c];
                #pragma unroll
                for (int j = 0; j < 4; ++j) {
                    const int rl = rbase + j;
                    if (row0 + rl < ce) {
                        float v = acc[mi][ni][j] + bv;
                        atomicAdd(&OutF[(size_t)lT[rl] * DMODEL + c], lW[rl] * v);
                    }
                }
            }
        }
    } else {
        // staged, coalesced stores via the LDS arena (128 x 128 u16, stride 136)
        __syncthreads();
        #pragma unroll
        for (int mi = 0; mi < 4; ++mi) {
            #pragma unroll
            for (int ni = 0; ni < 4; ++ni) {
                const int cl = wc * 64 + ni * 16 + fr;
                const float bv = bias[n0 + cl];
                #pragma unroll
                for (int j = 0; j < 4; ++j) {
                    float v = acc[mi][ni][j] + bv;
                    if (GELU) v = gelu_tanh(v);
                    const int rl = wr * 64 + mi * 16 + ks * 4 + j;
                    lsm[rl * 136 + cl] = f2bf(v);
                }
            }
        }
        __syncthreads();
        const int r2 = t >> 1, hcol = (t & 1) * 64;
        uint16_t* gp = OutBf + ((size_t)rbi * 128 + r2) * ncols + n0 + hcol;
        #pragma unroll
        for (int j2 = 0; j2 < 8; ++j2) {
            short8 v = *(const short8*)&lsm[r2 * 136 + hcol + j2 * 8];
            *(short8*)(gp + j2 * 8) = v;
        }
    }
}

// ---------------- combine: out[t] = w0*y2[p0] + w1*y2[p1] (gather, no atomics) ----
__global__ __launch_bounds__(256) void combine_kernel(
    const uint16_t* __restrict__ y2,
    const int* __restrict__ tpos0, const int* __restrict__ tpos1,
    const float* __restrict__ tw0, const float* __restrict__ tw1,
    const int* __restrict__ ebase, float* __restrict__ out)
{
    const int wid = threadIdx.x >> 6, lane = threadIdx.x & 63;
    const int t = blockIdx.x * 4 + wid;
    const int p0 = tpos0[t], p1 = tpos1[t];
    const int e0 = p0 >> 15, s0 = p0 & 32767;
    const int e1 = p1 >> 15, s1 = p1 & 32767;
    const bool v0 = s0 < CAP, v1 = s1 < CAP;
    const float w0 = v0 ? tw0[t] : 0.0f;
    const float w1 = v1 ? tw1[t] : 0.0f;
    const uint16_t* r0p = y2 + ((size_t)ebase[e0] + (v0 ? s0 : 0)) * DMODEL;
    const uint16_t* r1p = y2 + ((size_t)ebase[e1] + (v1 ? s1 : 0)) * DMODEL;
    float* op = out + (size_t)t * DMODEL;
    #pragma unroll
    for (int half = 0; half < 2; ++half) {
        const int off = half * 512 + lane * 8;
        short8 a = *(const short8*)(r0p + off);
        short8 b = *(const short8*)(r1p + off);
        float4 o0, o1;
        o0.x = w0 * bf2f((uint16_t)a[0]) + w1 * bf2f((uint16_t)b[0]);
        o0.y = w0 * bf2f((uint16_t)a[1]) + w1 * bf2f((uint16_t)b[1]);
        o0.z = w0 * bf2f((uint16_t)a[2]) + w1 * bf2f((uint16_t)b[2]);
        o0.w = w0 * bf2f((uint16_t)a[3]) + w1 * bf2f((uint16_t)b[3]);
        o1.x = w0 * bf2f((uint16_t)a[4]) + w1 * bf2f((uint16_t)b[4]);
        o1.y = w0 * bf2f((uint16_t)a[5]) + w1 * bf2f((uint16_t)b[5]);
        o1.z = w0 * bf2f((uint16_t)a[6]) + w1 * bf2f((uint16_t)b[6]);
        o1.w = w0 * bf2f((uint16_t)a[7]) + w1 * bf2f((uint16_t)b[7]);
        *(float4*)(op + off)     = o0;
        *(float4*)(op + off + 4) = o1;
    }
}

// ---------------- load-loss finalize ----------------
__global__ void finalize_kernel(const float* __restrict__ loadAcc, float* __restrict__ out) {
    if (threadIdx.x == 0) {
        float m = 0.f;
        #pragma unroll
        for (int e = 0; e < 8; ++e) m += loadAcc[e];
        m *= 0.125f;
        float v = 0.f;
        #pragma unroll
        for (int e = 0; e < 8; ++e) { float d0 = loadAcc[e] - m; v += d0 * d0; }
        v *= (1.0f / 7.0f);   // ddof=1
        out[(size_t)N_TOK * DMODEL] = W_LOAD_C * v / (m * m);
    }
}

extern "C" void kernel_launch(void* const* d_in, const int* in_sizes, int n_in,
                              void* d_out, int out_size, void* d_ws, size_t ws_size,
                              hipStream_t stream) {
    const float* x       = (const float*)d_in[0];
    const float* noise   = (const float*)d_in[1];
    const float* gate_w  = (const float*)d_in[2];
    const float* noise_w = (const float*)d_in[3];
    const float* w1      = (const float*)d_in[4];
    const float* b1      = (const float*)d_in[5];
    const float* w2      = (const float*)d_in[6];
    const float* b2      = (const float*)d_in[7];
    float* out = (float*)d_out;
    char* ws = (char*)d_ws;

    int*      cnt     = (int*)(ws + 0);
    float*    loadAcc = (float*)(ws + 256);
    int*      ebase   = (int*)(ws + 512);
    int*      be      = (int*)(ws + 1024);        // 264 ints
    int*      brow    = (int*)(ws + 3072);        // 264 ints
    int*      rowlist = (int*)(ws + 8192);        // 256 KiB
    int*      tpos0   = (int*)(ws + 270336);      // 64 KiB each
    int*      tpos1   = (int*)(ws + 335872);
    float*    tw0     = (float*)(ws + 401408);
    float*    tw1     = (float*)(ws + 466944);
    float*    slotw   = (float*)(ws + 532480);    // 256 KiB (fallback only)
    uint16_t* xb      = (uint16_t*)(ws + 794624); // 32 MiB
    uint16_t* w1t     = (uint16_t*)(ws + 34349056);  // 64 MiB
    uint16_t* w2t     = (uint16_t*)(ws + 101457920); // 64 MiB
    uint16_t* h       = (uint16_t*)(ws + 168566784); // 264*128 x 4096 bf16
    const size_t HOFF = 168566784ull;
    const size_t HSZ  = (size_t)MAXB2 * 128 * DFF * 2;     // 276,824,064
    uint16_t* y2      = (uint16_t*)(ws + HOFF + HSZ);      // packed y+b2 bf16
    const size_t Y2SZ = (size_t)MAXB2 * 128 * DMODEL * 2;  // 69,206,016
    const bool gatherPath = ws_size >= HOFF + HSZ + Y2SZ;

    hipMemsetAsync(ws, 0, 4096, stream);

    gating_kernel<<<2048, 512, 0, stream>>>(x, noise, gate_w, noise_w,
                                            cnt, loadAcc, rowlist, slotw,
                                            tpos0, tpos1, tw0, tw1, xb);
    scan_kernel<<<1, 256, 0, stream>>>(cnt, be, brow, ebase);
    transpose_w_kernel<<<dim3(128, 16, 8), 256, 0, stream>>>(w1, w1t, 1024, 4096);
    transpose_w_kernel<<<dim3(32, 64, 8), 256, 0, stream>>>(w2, w2t, 4096, 1024);
    finalize_kernel<<<1, 64, 0, stream>>>(loadAcc, out);

    if (gatherPath) {
        gemm_kernel<1024, 1, 1, 0, 1><<<dim3(32, MAXB2), 256, 0, stream>>>(
            xb, w1t, rowlist, slotw, cnt, be, brow, b1, h, nullptr, DFF, 0);
        gemm_kernel<4096, 0, 0, 0, 2><<<dim3(8, MAXB2), 256, 0, stream>>>(
            h, w2t, rowlist, slotw, cnt, be, brow, b2, y2, nullptr, DMODEL, 0);
        combine_kernel<<<4096, 256, 0, stream>>>(y2, tpos0, tpos1, tw0, tw1,
                                                 ebase, out);
    } else {
        // fallback: atomic combine (chunked if h doesn't fit)
        hipMemsetAsync(d_out, 0, (size_t)out_size * sizeof(float), stream);
        size_t avail = (ws_size > HOFF) ? ws_size - HOFF : 0;
        int nch = 8, bpc = (MAXB2 + 7) / 8;
        for (int c = 1; c <= 8; c <<= 1) {
            int b = (MAXB2 + c - 1) / c;
            if ((size_t)b * 128 * DFF * 2 <= avail) { nch = c; bpc = b; break; }
        }
        for (int c = 0; c < nch; ++c) {
            int bo = c * bpc;
            if (bo >= MAXB2) break;
            gemm_kernel<1024, 1, 1, 0, 0><<<dim3(32, bpc), 256, 0, stream>>>(
                xb, w1t, rowlist, slotw, cnt, be, brow, b1, h, nullptr, DFF, bo);
            gemm_kernel<4096, 0, 0, 1, 0><<<dim3(8, bpc), 256, 0, stream>>>(
                h, w2t, rowlist, slotw, cnt, be, brow, b2, nullptr, out, DMODEL, bo);
        }
    }
}